// Round 3
// baseline (218.273 us; speedup 1.0000x reference)
//
#include <hip/hip_runtime.h>
#include <math.h>

#define HH 512
#define WW 512
#define NPIX (HH*WW)
#define NBANDS 32
#define BAND (HH/NBANDS)          // 16 rows of output per wave (must be %4==0)
#define NS 28                      // ceil((BAND+10)/4)*4 streamed steps
#define PINF __builtin_huge_valf()

struct f8 { float4 a, b; };        // lane's 8 columns: a=cols[8L..8L+3], b=cols[8L+4..8L+7]

__device__ __forceinline__ f8 f8splat(float v){ f8 r; r.a = make_float4(v,v,v,v); r.b = r.a; return r; }

__device__ __forceinline__ f8 loadf8(const float* p){
    f8 r; r.a = *(const float4*)p; r.b = *(const float4*)(p + 4); return r;
}

__device__ __forceinline__ f8 f8min2(const f8& x, const f8& y){
    f8 r;
    r.a.x=fminf(x.a.x,y.a.x); r.a.y=fminf(x.a.y,y.a.y); r.a.z=fminf(x.a.z,y.a.z); r.a.w=fminf(x.a.w,y.a.w);
    r.b.x=fminf(x.b.x,y.b.x); r.b.y=fminf(x.b.y,y.b.y); r.b.z=fminf(x.b.z,y.b.z); r.b.w=fminf(x.b.w,y.b.w);
    return r;
}
__device__ __forceinline__ f8 f8min3(const f8& x, const f8& y, const f8& z){
    f8 r;
    r.a.x=fminf(fminf(x.a.x,y.a.x),z.a.x); r.a.y=fminf(fminf(x.a.y,y.a.y),z.a.y);
    r.a.z=fminf(fminf(x.a.z,y.a.z),z.a.z); r.a.w=fminf(fminf(x.a.w,y.a.w),z.a.w);
    r.b.x=fminf(fminf(x.b.x,y.b.x),z.b.x); r.b.y=fminf(fminf(x.b.y,y.b.y),z.b.y);
    r.b.z=fminf(fminf(x.b.z,y.b.z),z.b.z); r.b.w=fminf(fminf(x.b.w,y.b.w),z.b.w);
    return r;
}
__device__ __forceinline__ f8 f8max3(const f8& x, const f8& y, const f8& z){
    f8 r;
    r.a.x=fmaxf(fmaxf(x.a.x,y.a.x),z.a.x); r.a.y=fmaxf(fmaxf(x.a.y,y.a.y),z.a.y);
    r.a.z=fmaxf(fmaxf(x.a.z,y.a.z),z.a.z); r.a.w=fmaxf(fmaxf(x.a.w,y.a.w),z.a.w);
    r.b.x=fmaxf(fmaxf(x.b.x,y.b.x),z.b.x); r.b.y=fmaxf(fmaxf(x.b.y,y.b.y),z.b.y);
    r.b.z=fmaxf(fmaxf(x.b.z,y.b.z),z.b.z); r.b.w=fmaxf(fmaxf(x.b.w,y.b.w),z.b.w);
    return r;
}
// horizontal min over (c-1, c, c+1); out-of-image cols excluded via +INF
__device__ __forceinline__ f8 hmin3(const f8& x, int lane){
    float L = __shfl_up(x.b.w, 1);
    float R = __shfl_down(x.a.x, 1);
    if (lane == 0)  L = PINF;
    if (lane == 63) R = PINF;
    f8 r;
    r.a.x=fminf(fminf(L,    x.a.x),x.a.y);
    r.a.y=fminf(fminf(x.a.x,x.a.y),x.a.z);
    r.a.z=fminf(fminf(x.a.y,x.a.z),x.a.w);
    r.a.w=fminf(fminf(x.a.z,x.a.w),x.b.x);
    r.b.x=fminf(fminf(x.a.w,x.b.x),x.b.y);
    r.b.y=fminf(fminf(x.b.x,x.b.y),x.b.z);
    r.b.z=fminf(fminf(x.b.y,x.b.z),x.b.w);
    r.b.w=fminf(fminf(x.b.z,x.b.w),R);
    return r;
}
// horizontal max over (c-1, c, c+1); out-of-image cols excluded via -INF
__device__ __forceinline__ f8 hmax3(const f8& x, int lane){
    float L = __shfl_up(x.b.w, 1);
    float R = __shfl_down(x.a.x, 1);
    if (lane == 0)  L = -PINF;
    if (lane == 63) R = -PINF;
    f8 r;
    r.a.x=fmaxf(fmaxf(L,    x.a.x),x.a.y);
    r.a.y=fmaxf(fmaxf(x.a.x,x.a.y),x.a.z);
    r.a.z=fmaxf(fmaxf(x.a.y,x.a.z),x.a.w);
    r.a.w=fmaxf(fmaxf(x.a.z,x.a.w),x.b.x);
    r.b.x=fmaxf(fmaxf(x.a.w,x.b.x),x.b.y);
    r.b.y=fmaxf(fmaxf(x.b.x,x.b.y),x.b.z);
    r.b.z=fmaxf(fmaxf(x.b.y,x.b.z),x.b.w);
    r.b.w=fmaxf(fmaxf(x.b.z,x.b.w),R);
    return r;
}
// relu(p - d)
__device__ __forceinline__ f8 f8relu_sub(const f8& p, const f8& d){
    f8 r;
    r.a.x=fmaxf(p.a.x-d.a.x,0.f); r.a.y=fmaxf(p.a.y-d.a.y,0.f);
    r.a.z=fmaxf(p.a.z-d.a.z,0.f); r.a.w=fmaxf(p.a.w-d.a.w,0.f);
    r.b.x=fmaxf(p.b.x-d.b.x,0.f); r.b.y=fmaxf(p.b.y-d.b.y,0.f);
    r.b.z=fmaxf(p.b.z-d.b.z,0.f); r.b.w=fmaxf(p.b.w-d.b.w,0.f);
    return r;
}
// s += relu(d - s*d)
__device__ __forceinline__ void skupd(f8& s, const f8& d){
    s.a.x += fmaxf(fmaf(-s.a.x,d.a.x,d.a.x),0.f);
    s.a.y += fmaxf(fmaf(-s.a.y,d.a.y,d.a.y),0.f);
    s.a.z += fmaxf(fmaf(-s.a.z,d.a.z,d.a.z),0.f);
    s.a.w += fmaxf(fmaf(-s.a.w,d.a.w,d.a.w),0.f);
    s.b.x += fmaxf(fmaf(-s.b.x,d.b.x,d.b.x),0.f);
    s.b.y += fmaxf(fmaf(-s.b.y,d.b.y,d.b.y),0.f);
    s.b.z += fmaxf(fmaf(-s.b.z,d.b.z,d.b.z),0.f);
    s.b.w += fmaxf(fmaf(-s.b.w,d.b.w,d.b.w),0.f);
}

// One wave = one 16-row band of one (chain, image). Streams rows top->bottom,
// full 512-wide rows held across 64 lanes (8 cols/lane). Entire e1..e4 cascade,
// dilates, and skel updates in registers; horizontal via shfl; no LDS.
__global__ __launch_bounds__(256, 2)
void cldice_stream_k(const float* __restrict__ y_pred,
                     const float* __restrict__ y_true,
                     float2* __restrict__ partials, int B)
{
    const int lane = threadIdx.x & 63;
    const int wid  = threadIdx.x >> 6;
    const int wave = blockIdx.x * 4 + wid;
    const int nPerChain = B * NBANDS;
    if (wave >= 2 * nPerChain) return;
    const int chain = wave / nPerChain;
    const int rem   = wave - chain * nPerChain;
    const int im    = rem >> 5;                 // NBANDS == 32
    const int band  = rem & (NBANDS - 1);
    const int y0 = band * BAND;
    const int y1 = y0 + BAND;

    const float* __restrict__ img = (chain ? y_true : y_pred) + (size_t)im * NPIX + lane * 8;
    const float* __restrict__ oth = (chain ? y_pred : y_true) + (size_t)im * NPIX + lane * 8;

    // erode-input windows (value for out-of-range rows: +INF)
    f8 i1 = f8splat(PINF), i2 = i1;
    f8 e1p = i1, e1pp = i1, e2p = i1, e2pp = i1, e3p = i1, e3pp = i1;
    // dilate h-windows (out-of-range rows: -INF)
    f8 h1p = f8splat(-PINF), h1pp = h1p, h2p = h1p, h2pp = h1p;
    f8 h3p = h1p, h3pp = h1p, h4p = h1p, h4pp = h1p;
    // skel slots: row r lives in sk[r & 3]
    f8 sk[4]; sk[0] = f8splat(0.f); sk[1] = sk[0]; sk[2] = sk[0]; sk[3] = sk[0];
    float sa = 0.f, sb = 0.f;

    const int g0 = y0 - 5;
    f8 i0next = (g0 >= 0) ? loadf8(img + (size_t)g0 * WW) : f8splat(PINF);

    for (int sbase = 0; sbase < NS; sbase += 4) {
#pragma unroll
        for (int u = 0; u < 4; ++u) {
            const int s = sbase + u;
            const int g = g0 + s;                 // input row this step
            f8 i0 = i0next;
            {   // prefetch next input row (independent of this step's compute)
                const int gn = g + 1;
                const bool ld = (s + 1 < BAND + 10) && (gn >= 0) && (gn < HH);
                i0next = ld ? loadf8(img + (size_t)gn * WW) : f8splat(PINF);
            }
            // issue 'other' load early; consumed at the bottom of the body
            const int  yf  = g - 5;               // row finished this step
            const bool fin = (yf >= y0) && (yf < y1);
            f8 o = fin ? loadf8(oth + (size_t)yf * WW) : f8splat(0.f);

            // ---- stage 1: e1(g-1) ----
            f8 e1n = f8min2(f8min3(i2, i1, i0), hmin3(i1, lane));
            f8 h1n = hmax3(e1n, lane);
            f8 e1v = e1n;
            { const int r = g - 1; if (r < 0 || r >= HH) { e1v = f8splat(PINF); h1n = f8splat(-PINF); } }
            f8 d1 = f8max3(h1pp, h1p, h1n);               // dilate(e1) at row g-2
            sk[(u + 1) & 3] = f8relu_sub(i2, d1);         // birth: delta0(g-2)

            // ---- stage 2: e2(g-2) ----
            f8 e2n = f8min2(f8min3(e1pp, e1p, e1v), hmin3(e1p, lane));
            f8 h2n = hmax3(e2n, lane);
            f8 e2v = e2n;
            { const int r = g - 2; if (r < 0 || r >= HH) { e2v = f8splat(PINF); h2n = f8splat(-PINF); } }
            f8 d2 = f8max3(h2pp, h2p, h2n);               // dilate(e2) at row g-3
            skupd(sk[u & 3], f8relu_sub(e1pp, d2));       // delta1(g-3)

            // ---- stage 3: e3(g-3) ----
            f8 e3n = f8min2(f8min3(e2pp, e2p, e2v), hmin3(e2p, lane));
            f8 h3n = hmax3(e3n, lane);
            f8 e3v = e3n;
            { const int r = g - 3; if (r < 0 || r >= HH) { e3v = f8splat(PINF); h3n = f8splat(-PINF); } }
            f8 d3 = f8max3(h3pp, h3p, h3n);               // dilate(e3) at row g-4
            skupd(sk[(u + 3) & 3], f8relu_sub(e2pp, d3)); // delta2(g-4)

            // ---- stage 4: e4(g-4) ----
            f8 e4n = f8min2(f8min3(e3pp, e3p, e3v), hmin3(e3p, lane));
            f8 h4n = hmax3(e4n, lane);
            { const int r = g - 4; if (r < 0 || r >= HH) { h4n = f8splat(-PINF); } }
            f8 d4 = f8max3(h4pp, h4p, h4n);               // dilate(e4) at row g-5
            skupd(sk[(u + 2) & 3], f8relu_sub(e3pp, d4)); // delta3(g-5)

            // ---- finish row yf = g-5 ----
            if (fin) {
                const f8& S = sk[(u + 2) & 3];
                sa += ((S.a.x + S.a.y) + (S.a.z + S.a.w)) + ((S.b.x + S.b.y) + (S.b.z + S.b.w));
                sb += ((S.a.x * o.a.x + S.a.y * o.a.y) + (S.a.z * o.a.z + S.a.w * o.a.w))
                    + ((S.b.x * o.b.x + S.b.y * o.b.y) + (S.b.z * o.b.z + S.b.w * o.b.w));
            }
            // ---- shift windows ----
            i2 = i1; i1 = i0;
            e1pp = e1p; e1p = e1v;
            e2pp = e2p; e2p = e2v;
            e3pp = e3p; e3p = e3v;
            h1pp = h1p; h1p = h1n;
            h2pp = h2p; h2p = h2n;
            h3pp = h3p; h3p = h3n;
            h4pp = h4p; h4p = h4n;
        }
    }

#pragma unroll
    for (int off = 32; off; off >>= 1) {
        sa += __shfl_down(sa, off);
        sb += __shfl_down(sb, off);
    }
    if (lane == 0) partials[wave] = make_float2(sb, sa);   // (.x = sum skel*other, .y = sum skel)
}

__global__ void cldice_final_k(const float2* __restrict__ partials, int nW,
                               float* __restrict__ out)
{
    double s0 = 0, s1 = 0, s2 = 0, s3 = 0;
    for (int i = threadIdx.x; i < nW; i += 256) {
        float2 p = partials[i];        s0 += p.x; s1 += p.y;   // chain 0: skel_pred
        float2 q = partials[nW + i];   s2 += q.x; s3 += q.y;   // chain 1: skel_true
    }
#pragma unroll
    for (int off = 32; off; off >>= 1) {
        s0 += __shfl_down(s0, off);
        s1 += __shfl_down(s1, off);
        s2 += __shfl_down(s2, off);
        s3 += __shfl_down(s3, off);
    }
    __shared__ double sm[4][4];
    int wid = threadIdx.x >> 6, lane = threadIdx.x & 63;
    if (lane == 0) { sm[0][wid] = s0; sm[1][wid] = s1; sm[2][wid] = s2; sm[3][wid] = s3; }
    __syncthreads();
    if (threadIdx.x == 0) {
        double S0 = sm[0][0] + sm[0][1] + sm[0][2] + sm[0][3];
        double S1 = sm[1][0] + sm[1][1] + sm[1][2] + sm[1][3];
        double S2 = sm[2][0] + sm[2][1] + sm[2][2] + sm[2][3];
        double S3 = sm[3][0] + sm[3][1] + sm[3][2] + sm[3][3];
        double tprec = (S0 + 1.0) / (S1 + 1.0);
        double tsens = (S2 + 1.0) / (S3 + 1.0);
        out[0] = (float)(1.0 - 2.0 * (tprec * tsens) / (tprec + tsens));
    }
}

extern "C" void kernel_launch(void* const* d_in, const int* in_sizes, int n_in,
                              void* d_out, int out_size, void* d_ws, size_t ws_size,
                              hipStream_t stream)
{
    const float* y_pred = (const float*)d_in[0];
    const float* y_true = (const float*)d_in[1];
    const int B = in_sizes[0] / NPIX;          // 32 images

    float2* partials = (float2*)d_ws;          // 2*B*NBANDS float2 = 16 KB
    const int nWaves = 2 * B * NBANDS;
    const int blocks = (nWaves + 3) / 4;       // 4 waves per 256-thread block
    cldice_stream_k<<<blocks, 256, 0, stream>>>(y_pred, y_true, partials, B);

    cldice_final_k<<<1, 256, 0, stream>>>(partials, B * NBANDS, (float*)d_out);
}

// Round 4
// 200.958 us; speedup vs baseline: 1.0862x; 1.0862x over previous
//
#include <hip/hip_runtime.h>
#include <math.h>

#define HH 512
#define WW 512
#define NPIX (HH*WW)
#define NBANDS 32
#define BAND (HH/NBANDS)          // 16 output rows per wave
#define NS 28                     // ceil((BAND+10)/4)*4 streamed steps
#define PINF __builtin_huge_valf()

struct f8 { float4 a, b; };       // lane's 8 columns

__device__ __forceinline__ f8 f8splat(float v){ f8 r; r.a = make_float4(v,v,v,v); r.b = r.a; return r; }
__device__ __forceinline__ f8 loadf8(const float* p){
    f8 r; r.a = *(const float4*)p; r.b = *(const float4*)(p + 4); return r;
}
__device__ __forceinline__ f8 f8min2(const f8& x, const f8& y){
    f8 r;
    r.a.x=fminf(x.a.x,y.a.x); r.a.y=fminf(x.a.y,y.a.y); r.a.z=fminf(x.a.z,y.a.z); r.a.w=fminf(x.a.w,y.a.w);
    r.b.x=fminf(x.b.x,y.b.x); r.b.y=fminf(x.b.y,y.b.y); r.b.z=fminf(x.b.z,y.b.z); r.b.w=fminf(x.b.w,y.b.w);
    return r;
}
__device__ __forceinline__ f8 f8min3(const f8& x, const f8& y, const f8& z){
    f8 r;
    r.a.x=fminf(fminf(x.a.x,y.a.x),z.a.x); r.a.y=fminf(fminf(x.a.y,y.a.y),z.a.y);
    r.a.z=fminf(fminf(x.a.z,y.a.z),z.a.z); r.a.w=fminf(fminf(x.a.w,y.a.w),z.a.w);
    r.b.x=fminf(fminf(x.b.x,y.b.x),z.b.x); r.b.y=fminf(fminf(x.b.y,y.b.y),z.b.y);
    r.b.z=fminf(fminf(x.b.z,y.b.z),z.b.z); r.b.w=fminf(fminf(x.b.w,y.b.w),z.b.w);
    return r;
}
__device__ __forceinline__ f8 f8max3(const f8& x, const f8& y, const f8& z){
    f8 r;
    r.a.x=fmaxf(fmaxf(x.a.x,y.a.x),z.a.x); r.a.y=fmaxf(fmaxf(x.a.y,y.a.y),z.a.y);
    r.a.z=fmaxf(fmaxf(x.a.z,y.a.z),z.a.z); r.a.w=fmaxf(fmaxf(x.a.w,y.a.w),z.a.w);
    r.b.x=fmaxf(fmaxf(x.b.x,y.b.x),z.b.x); r.b.y=fmaxf(fmaxf(x.b.y,y.b.y),z.b.y);
    r.b.z=fmaxf(fmaxf(x.b.z,y.b.z),z.b.z); r.b.w=fmaxf(fmaxf(x.b.w,y.b.w),z.b.w);
    return r;
}
__device__ __forceinline__ f8 hmin3(const f8& x, int lane){
    float L = __shfl_up(x.b.w, 1);
    float R = __shfl_down(x.a.x, 1);
    if (lane == 0)  L = PINF;
    if (lane == 63) R = PINF;
    f8 r;
    r.a.x=fminf(fminf(L,    x.a.x),x.a.y);
    r.a.y=fminf(fminf(x.a.x,x.a.y),x.a.z);
    r.a.z=fminf(fminf(x.a.y,x.a.z),x.a.w);
    r.a.w=fminf(fminf(x.a.z,x.a.w),x.b.x);
    r.b.x=fminf(fminf(x.a.w,x.b.x),x.b.y);
    r.b.y=fminf(fminf(x.b.x,x.b.y),x.b.z);
    r.b.z=fminf(fminf(x.b.y,x.b.z),x.b.w);
    r.b.w=fminf(fminf(x.b.z,x.b.w),R);
    return r;
}
__device__ __forceinline__ f8 hmax3(const f8& x, int lane){
    float L = __shfl_up(x.b.w, 1);
    float R = __shfl_down(x.a.x, 1);
    if (lane == 0)  L = -PINF;
    if (lane == 63) R = -PINF;
    f8 r;
    r.a.x=fmaxf(fmaxf(L,    x.a.x),x.a.y);
    r.a.y=fmaxf(fmaxf(x.a.x,x.a.y),x.a.z);
    r.a.z=fmaxf(fmaxf(x.a.y,x.a.z),x.a.w);
    r.a.w=fmaxf(fmaxf(x.a.z,x.a.w),x.b.x);
    r.b.x=fmaxf(fmaxf(x.a.w,x.b.x),x.b.y);
    r.b.y=fmaxf(fmaxf(x.b.x,x.b.y),x.b.z);
    r.b.z=fmaxf(fmaxf(x.b.y,x.b.z),x.b.w);
    r.b.w=fmaxf(fmaxf(x.b.z,x.b.w),R);
    return r;
}
__device__ __forceinline__ f8 f8relu_sub(const f8& p, const f8& d){
    f8 r;
    r.a.x=fmaxf(p.a.x-d.a.x,0.f); r.a.y=fmaxf(p.a.y-d.a.y,0.f);
    r.a.z=fmaxf(p.a.z-d.a.z,0.f); r.a.w=fmaxf(p.a.w-d.a.w,0.f);
    r.b.x=fmaxf(p.b.x-d.b.x,0.f); r.b.y=fmaxf(p.b.y-d.b.y,0.f);
    r.b.z=fmaxf(p.b.z-d.b.z,0.f); r.b.w=fmaxf(p.b.w-d.b.w,0.f);
    return r;
}
__device__ __forceinline__ void skupd(f8& s, const f8& d){
    s.a.x += fmaxf(fmaf(-s.a.x,d.a.x,d.a.x),0.f);
    s.a.y += fmaxf(fmaf(-s.a.y,d.a.y,d.a.y),0.f);
    s.a.z += fmaxf(fmaf(-s.a.z,d.a.z,d.a.z),0.f);
    s.a.w += fmaxf(fmaf(-s.a.w,d.a.w,d.a.w),0.f);
    s.b.x += fmaxf(fmaf(-s.b.x,d.b.x,d.b.x),0.f);
    s.b.y += fmaxf(fmaf(-s.b.y,d.b.y,d.b.y),0.f);
    s.b.z += fmaxf(fmaf(-s.b.z,d.b.z,d.b.z),0.f);
    s.b.w += fmaxf(fmaf(-s.b.w,d.b.w,d.b.w),0.f);
}

// One pipeline step. Window "shift" is done by writing the new row into the
// *pp* slot and swapping the (p, pp) argument names at the next call site —
// no array indexing anywhere, so everything stays in VGPRs (rule #20).
__device__ __forceinline__ void step_body(
    int g, int s, int y0, int y1, int lane,
    const float* __restrict__ img, const float* __restrict__ oth,
    f8& i2, f8& i1, f8& i0next,
    f8& e1p, f8& e1pp, f8& e2p, f8& e2pp, f8& e3p, f8& e3pp,
    f8& h1p, f8& h1pp, f8& h2p, f8& h2pp, f8& h3p, f8& h3pp,
    f8& h4p, f8& h4pp,
    f8& skBirth, f8& skD1, f8& skD2, f8& skFin,
    float& sa, float& sb)
{
    f8 i0 = i0next;
    {   // prefetch next input row
        const int gn = g + 1;
        const bool ld = (s + 1 < BAND + 10) && (gn >= 0) && (gn < HH);
        i0next = ld ? loadf8(img + (size_t)gn * WW) : f8splat(PINF);
    }
    const int  yf  = g - 5;                  // row finished this step
    const bool fin = (yf >= y0) && (yf < y1);
    f8 o = fin ? loadf8(oth + (size_t)yf * WW) : f8splat(0.f);

    // ---- stage 1: e1(g-1) ----
    f8 e1n = f8min2(f8min3(i2, i1, i0), hmin3(i1, lane));
    f8 h1n = hmax3(e1n, lane);
    { const int r = g - 1; if (r < 0 || r >= HH) { e1n = f8splat(PINF); h1n = f8splat(-PINF); } }
    f8 d1 = f8max3(h1pp, h1p, h1n);          // dilate(e1) at row g-2
    skBirth = f8relu_sub(i2, d1);            // skel init for row g-2

    // ---- stage 2: e2(g-2) ----
    f8 e2n = f8min2(f8min3(e1pp, e1p, e1n), hmin3(e1p, lane));
    f8 h2n = hmax3(e2n, lane);
    { const int r = g - 2; if (r < 0 || r >= HH) { e2n = f8splat(PINF); h2n = f8splat(-PINF); } }
    f8 d2 = f8max3(h2pp, h2p, h2n);          // dilate(e2) at row g-3
    skupd(skD1, f8relu_sub(e1pp, d2));

    // ---- stage 3: e3(g-3) ----
    f8 e3n = f8min2(f8min3(e2pp, e2p, e2n), hmin3(e2p, lane));
    f8 h3n = hmax3(e3n, lane);
    { const int r = g - 3; if (r < 0 || r >= HH) { e3n = f8splat(PINF); h3n = f8splat(-PINF); } }
    f8 d3 = f8max3(h3pp, h3p, h3n);          // dilate(e3) at row g-4
    skupd(skD2, f8relu_sub(e2pp, d3));

    // ---- stage 4: e4(g-4) ----
    f8 e4n = f8min2(f8min3(e3pp, e3p, e3n), hmin3(e3p, lane));
    f8 h4n = hmax3(e4n, lane);
    { const int r = g - 4; if (r < 0 || r >= HH) { h4n = f8splat(-PINF); } }
    f8 d4 = f8max3(h4pp, h4p, h4n);          // dilate(e4) at row g-5
    skupd(skFin, f8relu_sub(e3pp, d4));

    // ---- finish row g-5 ----
    if (fin) {
        sa += ((skFin.a.x + skFin.a.y) + (skFin.a.z + skFin.a.w))
            + ((skFin.b.x + skFin.b.y) + (skFin.b.z + skFin.b.w));
        sb += ((skFin.a.x * o.a.x + skFin.a.y * o.a.y) + (skFin.a.z * o.a.z + skFin.a.w * o.a.w))
            + ((skFin.b.x * o.b.x + skFin.b.y * o.b.y) + (skFin.b.z * o.b.z + skFin.b.w * o.b.w));
    }

    // ---- shift: new row overwrites pp slot; caller swaps (p,pp) next call ----
    i2 = i1; i1 = i0;
    e1pp = e1n; e2pp = e2n; e3pp = e3n;
    h1pp = h1n; h2pp = h2n; h3pp = h3n; h4pp = h4n;
}

__global__ __launch_bounds__(256, 2)
void cldice_stream_k(const float* __restrict__ y_pred,
                     const float* __restrict__ y_true,
                     float2* __restrict__ partials, int B)
{
    const int lane = threadIdx.x & 63;
    const int wid  = threadIdx.x >> 6;
    const int wave = blockIdx.x * 4 + wid;
    const int nPerChain = B * NBANDS;
    if (wave >= 2 * nPerChain) return;
    const int chain = wave / nPerChain;
    const int rem   = wave - chain * nPerChain;
    const int im    = rem >> 5;                 // NBANDS == 32
    const int band  = rem & (NBANDS - 1);
    const int y0 = band * BAND;
    const int y1 = y0 + BAND;

    const float* __restrict__ img = (chain ? y_true : y_pred) + (size_t)im * NPIX + lane * 8;
    const float* __restrict__ oth = (chain ? y_pred : y_true) + (size_t)im * NPIX + lane * 8;

    // named register state — NO arrays anywhere
    f8 i2 = f8splat(PINF), i1 = i2;
    f8 e1A = i2, e1B = i2, e2A = i2, e2B = i2, e3A = i2, e3B = i2;
    f8 h1A = f8splat(-PINF), h1B = h1A, h2A = h1A, h2B = h1A;
    f8 h3A = h1A, h3B = h1A, h4A = h1A, h4B = h1A;
    f8 sk0 = f8splat(0.f), sk1 = sk0, sk2 = sk0, sk3 = sk0;
    float sa = 0.f, sb = 0.f;

    const int g0 = y0 - 5;
    f8 i0next = (g0 >= 0) ? loadf8(img + (size_t)g0 * WW) : f8splat(PINF);

#define STEP(U, E1P,E1PP, E2P,E2PP, E3P,E3PP, H1P,H1PP, H2P,H2PP, H3P,H3PP, H4P,H4PP, SKB,SKD1,SKD2,SKF) \
    step_body(g0 + sbase + U, sbase + U, y0, y1, lane, img, oth, i2, i1, i0next, \
              E1P,E1PP, E2P,E2PP, E3P,E3PP, H1P,H1PP, H2P,H2PP, H3P,H3PP, H4P,H4PP, \
              SKB,SKD1,SKD2,SKF, sa, sb)

    for (int sbase = 0; sbase < NS; sbase += 4) {
        STEP(0, e1A,e1B, e2A,e2B, e3A,e3B, h1A,h1B, h2A,h2B, h3A,h3B, h4A,h4B, sk1,sk0,sk3,sk2);
        STEP(1, e1B,e1A, e2B,e2A, e3B,e3A, h1B,h1A, h2B,h2A, h3B,h3A, h4B,h4A, sk2,sk1,sk0,sk3);
        STEP(2, e1A,e1B, e2A,e2B, e3A,e3B, h1A,h1B, h2A,h2B, h3A,h3B, h4A,h4B, sk3,sk2,sk1,sk0);
        STEP(3, e1B,e1A, e2B,e2A, e3B,e3A, h1B,h1A, h2B,h2A, h3B,h3A, h4B,h4A, sk0,sk3,sk2,sk1);
    }
#undef STEP

#pragma unroll
    for (int off = 32; off; off >>= 1) {
        sa += __shfl_down(sa, off);
        sb += __shfl_down(sb, off);
    }
    if (lane == 0) partials[wave] = make_float2(sb, sa);   // (.x = sum skel*other, .y = sum skel)
}

__global__ void cldice_final_k(const float2* __restrict__ partials, int nW,
                               float* __restrict__ out)
{
    double s0 = 0, s1 = 0, s2 = 0, s3 = 0;
    for (int i = threadIdx.x; i < nW; i += 256) {
        float2 p = partials[i];        s0 += p.x; s1 += p.y;   // chain 0: skel_pred
        float2 q = partials[nW + i];   s2 += q.x; s3 += q.y;   // chain 1: skel_true
    }
#pragma unroll
    for (int off = 32; off; off >>= 1) {
        s0 += __shfl_down(s0, off);
        s1 += __shfl_down(s1, off);
        s2 += __shfl_down(s2, off);
        s3 += __shfl_down(s3, off);
    }
    __shared__ double sm[4][4];
    int wid = threadIdx.x >> 6, lane = threadIdx.x & 63;
    if (lane == 0) { sm[0][wid] = s0; sm[1][wid] = s1; sm[2][wid] = s2; sm[3][wid] = s3; }
    __syncthreads();
    if (threadIdx.x == 0) {
        double S0 = sm[0][0] + sm[0][1] + sm[0][2] + sm[0][3];
        double S1 = sm[1][0] + sm[1][1] + sm[1][2] + sm[1][3];
        double S2 = sm[2][0] + sm[2][1] + sm[2][2] + sm[2][3];
        double S3 = sm[3][0] + sm[3][1] + sm[3][2] + sm[3][3];
        double tprec = (S0 + 1.0) / (S1 + 1.0);
        double tsens = (S2 + 1.0) / (S3 + 1.0);
        out[0] = (float)(1.0 - 2.0 * (tprec * tsens) / (tprec + tsens));
    }
}

extern "C" void kernel_launch(void* const* d_in, const int* in_sizes, int n_in,
                              void* d_out, int out_size, void* d_ws, size_t ws_size,
                              hipStream_t stream)
{
    const float* y_pred = (const float*)d_in[0];
    const float* y_true = (const float*)d_in[1];
    const int B = in_sizes[0] / NPIX;          // 32 images

    float2* partials = (float2*)d_ws;          // 2*B*NBANDS float2 = 16 KB
    const int nWaves = 2 * B * NBANDS;
    const int blocks = (nWaves + 3) / 4;       // 4 waves per 256-thread block
    cldice_stream_k<<<blocks, 256, 0, stream>>>(y_pred, y_true, partials, B);

    cldice_final_k<<<1, 256, 0, stream>>>(partials, B * NBANDS, (float*)d_out);
}

// Round 5
// 200.070 us; speedup vs baseline: 1.0910x; 1.0044x over previous
//
#include <hip/hip_runtime.h>
#include <math.h>

#define HH 512
#define WW 512
#define NPIX (HH*WW)
#define NBANDS 32
#define BAND (HH/NBANDS)          // 16 output rows per wave
#define NS 28                     // ceil((BAND+10)/4)*4 streamed steps
#define PINF __builtin_huge_valf()

struct f8 { float4 a, b; };       // lane's 8 columns

__device__ __forceinline__ f8 f8splat(float v){ f8 r; r.a = make_float4(v,v,v,v); r.b = r.a; return r; }
__device__ __forceinline__ f8 loadf8(const float* p){
    f8 r; r.a = *(const float4*)p; r.b = *(const float4*)(p + 4); return r;
}
__device__ __forceinline__ f8 f8min2(const f8& x, const f8& y){
    f8 r;
    r.a.x=fminf(x.a.x,y.a.x); r.a.y=fminf(x.a.y,y.a.y); r.a.z=fminf(x.a.z,y.a.z); r.a.w=fminf(x.a.w,y.a.w);
    r.b.x=fminf(x.b.x,y.b.x); r.b.y=fminf(x.b.y,y.b.y); r.b.z=fminf(x.b.z,y.b.z); r.b.w=fminf(x.b.w,y.b.w);
    return r;
}
__device__ __forceinline__ f8 f8min3(const f8& x, const f8& y, const f8& z){
    f8 r;
    r.a.x=fminf(fminf(x.a.x,y.a.x),z.a.x); r.a.y=fminf(fminf(x.a.y,y.a.y),z.a.y);
    r.a.z=fminf(fminf(x.a.z,y.a.z),z.a.z); r.a.w=fminf(fminf(x.a.w,y.a.w),z.a.w);
    r.b.x=fminf(fminf(x.b.x,y.b.x),z.b.x); r.b.y=fminf(fminf(x.b.y,y.b.y),z.b.y);
    r.b.z=fminf(fminf(x.b.z,y.b.z),z.b.z); r.b.w=fminf(fminf(x.b.w,y.b.w),z.b.w);
    return r;
}
__device__ __forceinline__ f8 f8max3(const f8& x, const f8& y, const f8& z){
    f8 r;
    r.a.x=fmaxf(fmaxf(x.a.x,y.a.x),z.a.x); r.a.y=fmaxf(fmaxf(x.a.y,y.a.y),z.a.y);
    r.a.z=fmaxf(fmaxf(x.a.z,y.a.z),z.a.z); r.a.w=fmaxf(fmaxf(x.a.w,y.a.w),z.a.w);
    r.b.x=fmaxf(fmaxf(x.b.x,y.b.x),z.b.x); r.b.y=fmaxf(fmaxf(x.b.y,y.b.y),z.b.y);
    r.b.z=fmaxf(fmaxf(x.b.z,y.b.z),z.b.z); r.b.w=fmaxf(fmaxf(x.b.w,y.b.w),z.b.w);
    return r;
}
__device__ __forceinline__ f8 hmin3(const f8& x, int lane){
    float L = __shfl_up(x.b.w, 1);
    float R = __shfl_down(x.a.x, 1);
    if (lane == 0)  L = PINF;
    if (lane == 63) R = PINF;
    f8 r;
    r.a.x=fminf(fminf(L,    x.a.x),x.a.y);
    r.a.y=fminf(fminf(x.a.x,x.a.y),x.a.z);
    r.a.z=fminf(fminf(x.a.y,x.a.z),x.a.w);
    r.a.w=fminf(fminf(x.a.z,x.a.w),x.b.x);
    r.b.x=fminf(fminf(x.a.w,x.b.x),x.b.y);
    r.b.y=fminf(fminf(x.b.x,x.b.y),x.b.z);
    r.b.z=fminf(fminf(x.b.y,x.b.z),x.b.w);
    r.b.w=fminf(fminf(x.b.z,x.b.w),R);
    return r;
}
__device__ __forceinline__ f8 hmax3(const f8& x, int lane){
    float L = __shfl_up(x.b.w, 1);
    float R = __shfl_down(x.a.x, 1);
    if (lane == 0)  L = -PINF;
    if (lane == 63) R = -PINF;
    f8 r;
    r.a.x=fmaxf(fmaxf(L,    x.a.x),x.a.y);
    r.a.y=fmaxf(fmaxf(x.a.x,x.a.y),x.a.z);
    r.a.z=fmaxf(fmaxf(x.a.y,x.a.z),x.a.w);
    r.a.w=fmaxf(fmaxf(x.a.z,x.a.w),x.b.x);
    r.b.x=fmaxf(fmaxf(x.a.w,x.b.x),x.b.y);
    r.b.y=fmaxf(fmaxf(x.b.x,x.b.y),x.b.z);
    r.b.z=fmaxf(fmaxf(x.b.y,x.b.z),x.b.w);
    r.b.w=fmaxf(fmaxf(x.b.z,x.b.w),R);
    return r;
}
__device__ __forceinline__ f8 f8relu_sub(const f8& p, const f8& d){
    f8 r;
    r.a.x=fmaxf(p.a.x-d.a.x,0.f); r.a.y=fmaxf(p.a.y-d.a.y,0.f);
    r.a.z=fmaxf(p.a.z-d.a.z,0.f); r.a.w=fmaxf(p.a.w-d.a.w,0.f);
    r.b.x=fmaxf(p.b.x-d.b.x,0.f); r.b.y=fmaxf(p.b.y-d.b.y,0.f);
    r.b.z=fmaxf(p.b.z-d.b.z,0.f); r.b.w=fmaxf(p.b.w-d.b.w,0.f);
    return r;
}
__device__ __forceinline__ void skupd(f8& s, const f8& d){
    s.a.x += fmaxf(fmaf(-s.a.x,d.a.x,d.a.x),0.f);
    s.a.y += fmaxf(fmaf(-s.a.y,d.a.y,d.a.y),0.f);
    s.a.z += fmaxf(fmaf(-s.a.z,d.a.z,d.a.z),0.f);
    s.a.w += fmaxf(fmaf(-s.a.w,d.a.w,d.a.w),0.f);
    s.b.x += fmaxf(fmaf(-s.b.x,d.b.x,d.b.x),0.f);
    s.b.y += fmaxf(fmaf(-s.b.y,d.b.y,d.b.y),0.f);
    s.b.z += fmaxf(fmaf(-s.b.z,d.b.z,d.b.z),0.f);
    s.b.w += fmaxf(fmaf(-s.b.w,d.b.w,d.b.w),0.f);
}

// One pipeline step. Window "shift" by name rotation at the call site — no
// array indexing anywhere (rule #20), everything stays in VGPRs.
__device__ __forceinline__ void step_body(
    int g, int s, int y0, int y1, int lane,
    const float* __restrict__ img, const float* __restrict__ oth,
    f8& i2, f8& i1, f8& i0next,
    f8& e1p, f8& e1pp, f8& e2p, f8& e2pp, f8& e3p, f8& e3pp,
    f8& h1p, f8& h1pp, f8& h2p, f8& h2pp, f8& h3p, f8& h3pp,
    f8& h4p, f8& h4pp,
    f8& skBirth, f8& skD1, f8& skD2, f8& skFin,
    float& sa, float& sb)
{
    f8 i0 = i0next;
    {   // prefetch next input row
        const int gn = g + 1;
        const bool ld = (s + 1 < BAND + 10) && (gn >= 0) && (gn < HH);
        i0next = ld ? loadf8(img + (size_t)gn * WW) : f8splat(PINF);
    }
    const int  yf  = g - 5;                  // row finished this step
    const bool fin = (yf >= y0) && (yf < y1);
    f8 o = fin ? loadf8(oth + (size_t)yf * WW) : f8splat(0.f);

    // ---- stage 1: e1(g-1) ----
    f8 e1n = f8min2(f8min3(i2, i1, i0), hmin3(i1, lane));
    f8 h1n = hmax3(e1n, lane);
    { const int r = g - 1; if (r < 0 || r >= HH) { e1n = f8splat(PINF); h1n = f8splat(-PINF); } }
    f8 d1 = f8max3(h1pp, h1p, h1n);          // dilate(e1) at row g-2
    skBirth = f8relu_sub(i2, d1);            // skel init for row g-2

    // ---- stage 2: e2(g-2) ----
    f8 e2n = f8min2(f8min3(e1pp, e1p, e1n), hmin3(e1p, lane));
    f8 h2n = hmax3(e2n, lane);
    { const int r = g - 2; if (r < 0 || r >= HH) { e2n = f8splat(PINF); h2n = f8splat(-PINF); } }
    f8 d2 = f8max3(h2pp, h2p, h2n);          // dilate(e2) at row g-3
    skupd(skD1, f8relu_sub(e1pp, d2));

    // ---- stage 3: e3(g-3) ----
    f8 e3n = f8min2(f8min3(e2pp, e2p, e2n), hmin3(e2p, lane));
    f8 h3n = hmax3(e3n, lane);
    { const int r = g - 3; if (r < 0 || r >= HH) { e3n = f8splat(PINF); h3n = f8splat(-PINF); } }
    f8 d3 = f8max3(h3pp, h3p, h3n);          // dilate(e3) at row g-4
    skupd(skD2, f8relu_sub(e2pp, d3));

    // ---- stage 4: e4(g-4) ----
    f8 e4n = f8min2(f8min3(e3pp, e3p, e3n), hmin3(e3p, lane));
    f8 h4n = hmax3(e4n, lane);
    { const int r = g - 4; if (r < 0 || r >= HH) { h4n = f8splat(-PINF); } }
    f8 d4 = f8max3(h4pp, h4p, h4n);          // dilate(e4) at row g-5
    skupd(skFin, f8relu_sub(e3pp, d4));

    // ---- finish row g-5 ----
    if (fin) {
        sa += ((skFin.a.x + skFin.a.y) + (skFin.a.z + skFin.a.w))
            + ((skFin.b.x + skFin.b.y) + (skFin.b.z + skFin.b.w));
        sb += ((skFin.a.x * o.a.x + skFin.a.y * o.a.y) + (skFin.a.z * o.a.z + skFin.a.w * o.a.w))
            + ((skFin.b.x * o.b.x + skFin.b.y * o.b.y) + (skFin.b.z * o.b.z + skFin.b.w * o.b.w));
    }

    // ---- shift: new row overwrites pp slot; caller swaps (p,pp) next call ----
    i2 = i1; i1 = i0;
    e1pp = e1n; e2pp = e2n; e3pp = e3n;
    h1pp = h1n; h2pp = h2n; h3pp = h3n; h4pp = h4n;
}

__global__ __launch_bounds__(256)
__attribute__((amdgpu_waves_per_eu(2, 2)))   // pin 2 waves/EU -> 256-VGPR budget, no scratch
void cldice_stream_k(const float* __restrict__ y_pred,
                     const float* __restrict__ y_true,
                     float2* __restrict__ partials, int B)
{
    const int lane = threadIdx.x & 63;
    const int wid  = threadIdx.x >> 6;
    const int wave = blockIdx.x * 4 + wid;
    const int nPerChain = B * NBANDS;
    if (wave >= 2 * nPerChain) return;
    const int chain = wave / nPerChain;
    const int rem   = wave - chain * nPerChain;
    const int im    = rem >> 5;                 // NBANDS == 32
    const int band  = rem & (NBANDS - 1);
    const int y0 = band * BAND;
    const int y1 = y0 + BAND;

    const float* __restrict__ img = (chain ? y_true : y_pred) + (size_t)im * NPIX + lane * 8;
    const float* __restrict__ oth = (chain ? y_pred : y_true) + (size_t)im * NPIX + lane * 8;

    // named register state — NO arrays anywhere
    f8 i2 = f8splat(PINF), i1 = i2;
    f8 e1A = i2, e1B = i2, e2A = i2, e2B = i2, e3A = i2, e3B = i2;
    f8 h1A = f8splat(-PINF), h1B = h1A, h2A = h1A, h2B = h1A;
    f8 h3A = h1A, h3B = h1A, h4A = h1A, h4B = h1A;
    f8 sk0 = f8splat(0.f), sk1 = sk0, sk2 = sk0, sk3 = sk0;
    float sa = 0.f, sb = 0.f;

    const int g0 = y0 - 5;
    f8 i0next = (g0 >= 0) ? loadf8(img + (size_t)g0 * WW) : f8splat(PINF);

#define STEP(U, E1P,E1PP, E2P,E2PP, E3P,E3PP, H1P,H1PP, H2P,H2PP, H3P,H3PP, H4P,H4PP, SKB,SKD1,SKD2,SKF) \
    step_body(g0 + sbase + U, sbase + U, y0, y1, lane, img, oth, i2, i1, i0next, \
              E1P,E1PP, E2P,E2PP, E3P,E3PP, H1P,H1PP, H2P,H2PP, H3P,H3PP, H4P,H4PP, \
              SKB,SKD1,SKD2,SKF, sa, sb)

    for (int sbase = 0; sbase < NS; sbase += 4) {
        STEP(0, e1A,e1B, e2A,e2B, e3A,e3B, h1A,h1B, h2A,h2B, h3A,h3B, h4A,h4B, sk1,sk0,sk3,sk2);
        STEP(1, e1B,e1A, e2B,e2A, e3B,e3A, h1B,h1A, h2B,h2A, h3B,h3A, h4B,h4A, sk2,sk1,sk0,sk3);
        STEP(2, e1A,e1B, e2A,e2B, e3A,e3B, h1A,h1B, h2A,h2B, h3A,h3B, h4A,h4B, sk3,sk2,sk1,sk0);
        STEP(3, e1B,e1A, e2B,e2A, e3B,e3A, h1B,h1A, h2B,h2A, h3B,h3A, h4B,h4A, sk0,sk3,sk2,sk1);
    }
#undef STEP

#pragma unroll
    for (int off = 32; off; off >>= 1) {
        sa += __shfl_down(sa, off);
        sb += __shfl_down(sb, off);
    }
    if (lane == 0) partials[wave] = make_float2(sb, sa);   // (.x = sum skel*other, .y = sum skel)
}

__global__ void cldice_final_k(const float2* __restrict__ partials, int nW,
                               float* __restrict__ out)
{
    double s0 = 0, s1 = 0, s2 = 0, s3 = 0;
    for (int i = threadIdx.x; i < nW; i += 256) {
        float2 p = partials[i];        s0 += p.x; s1 += p.y;   // chain 0: skel_pred
        float2 q = partials[nW + i];   s2 += q.x; s3 += q.y;   // chain 1: skel_true
    }
#pragma unroll
    for (int off = 32; off; off >>= 1) {
        s0 += __shfl_down(s0, off);
        s1 += __shfl_down(s1, off);
        s2 += __shfl_down(s2, off);
        s3 += __shfl_down(s3, off);
    }
    __shared__ double sm[4][4];
    int wid = threadIdx.x >> 6, lane = threadIdx.x & 63;
    if (lane == 0) { sm[0][wid] = s0; sm[1][wid] = s1; sm[2][wid] = s2; sm[3][wid] = s3; }
    __syncthreads();
    if (threadIdx.x == 0) {
        double S0 = sm[0][0] + sm[0][1] + sm[0][2] + sm[0][3];
        double S1 = sm[1][0] + sm[1][1] + sm[1][2] + sm[1][3];
        double S2 = sm[2][0] + sm[2][1] + sm[2][2] + sm[2][3];
        double S3 = sm[3][0] + sm[3][1] + sm[3][2] + sm[3][3];
        double tprec = (S0 + 1.0) / (S1 + 1.0);
        double tsens = (S2 + 1.0) / (S3 + 1.0);
        out[0] = (float)(1.0 - 2.0 * (tprec * tsens) / (tprec + tsens));
    }
}

extern "C" void kernel_launch(void* const* d_in, const int* in_sizes, int n_in,
                              void* d_out, int out_size, void* d_ws, size_t ws_size,
                              hipStream_t stream)
{
    const float* y_pred = (const float*)d_in[0];
    const float* y_true = (const float*)d_in[1];
    const int B = in_sizes[0] / NPIX;          // 32 images

    float2* partials = (float2*)d_ws;          // 2*B*NBANDS float2 = 16 KB
    const int nWaves = 2 * B * NBANDS;
    const int blocks = (nWaves + 3) / 4;       // 4 waves per 256-thread block
    cldice_stream_k<<<blocks, 256, 0, stream>>>(y_pred, y_true, partials, B);

    cldice_final_k<<<1, 256, 0, stream>>>(partials, B * NBANDS, (float*)d_out);
}

// Round 6
// 97.929 us; speedup vs baseline: 2.2289x; 2.0430x over previous
//
#include <hip/hip_runtime.h>
#include <math.h>

#define HH 512
#define WW 512
#define NPIX (HH*WW)

#define TS   64          // output tile
#define BR   74          // buffer rows: 5 + 64 + 5
#define BC   84          // buffer cols: 8 + 64 + 5 (+7 pad) -> row stride 84 ≡ 20 (mod 32 banks)
#define BC4  (BC/4)
#define ROFF 5           // center row offset in buffer
#define COFF 8           // center col offset in buffer (4-aligned)

// One block = one 64x64 tile of one image of one chain. Computes the entire
// soft_skel chain (e1..e4, 4 open/skel updates) in LDS, skel in registers,
// emits a single float2 partial (sum(skel*other), sum(skel)).
__global__ __launch_bounds__(256, 3)
void cldice_fused_k(const float* __restrict__ y_pred,
                    const float* __restrict__ y_true,
                    float2* __restrict__ partials)
{
    __shared__ float buf[2][BR][BC];
    __shared__ float redA[4], redB[4];

    const int tid   = threadIdx.x;
    const int chain = blockIdx.z;
    const int im    = blockIdx.y;
    const int tileY = blockIdx.x >> 3;
    const int tileX = blockIdx.x & 7;
    const int y0 = tileY * TS;
    const int x0 = tileX * TS;

    const float* __restrict__ imgp = (chain ? y_true : y_pred) + (size_t)im * NPIX;
    const float* __restrict__ othp = (chain ? y_pred : y_true) + (size_t)im * NPIX;

    // ---- load tile + halo, replicate-clamped at image borders ----
    for (int i = tid; i < BR * BC4; i += 256) {
        int r  = i / BC4;
        int c0 = (i - r * BC4) * 4;
        int gy = y0 - ROFF + r;
        gy = min(max(gy, 0), HH - 1);
        int gx = x0 - COFF + c0;
        const float* rowp = imgp + (size_t)gy * WW;
        float4 v;
        if ((unsigned)gx <= (unsigned)(WW - 4)) {
            v = *(const float4*)(rowp + gx);
        } else {
            int g0 = min(max(gx + 0, 0), WW - 1);
            int g1 = min(max(gx + 1, 0), WW - 1);
            int g2 = min(max(gx + 2, 0), WW - 1);
            int g3 = min(max(gx + 3, 0), WW - 1);
            v.x = rowp[g0]; v.y = rowp[g1]; v.z = rowp[g2]; v.w = rowp[g3];
        }
        *(float4*)&buf[0][r][c0] = v;
    }
    __syncthreads();

    const int ty = tid >> 4;           // 16x16 threads over the 64x64 center
    const int tx = tid & 15;
    const int Rr = ROFF + ty * 4;      // this thread's 4 center rows
    const int Cc = COFF + tx * 4;      // this thread's aligned 4-col group

    // image-boundary clamps for the dilate (max must exclude out-of-image)
    const int  rLoD  = (y0 == 0)       ? ROFF            : 0;
    const int  rHiD  = (y0 + TS == HH) ? (ROFF + TS - 1) : (BR - 1);
    const bool leftE  = (x0 == 0)       && (tx == 0);
    const bool rightE = (x0 + TS == WW) && (tx == 15);

    float4 skel[4];
    #pragma unroll
    for (int i = 0; i < 4; ++i) skel[i] = make_float4(0.f, 0.f, 0.f, 0.f);

    int cur = 0;
    #pragma unroll
    for (int stage = 0; stage < 4; ++stage) {
        const int k = stage + 1;                  // erosion depth this stage
        const float (*S)[BC]   = buf[cur];        // e_{k-1} (stage 0: img)
        float       (*Dst)[BC] = buf[cur ^ 1];    // e_k

        // erode rows [k, BR-1-k] only — exactly what later consumers need
        // (dilate d_k reads rows [4,69]; e_{k+1} reads [k, 73-k]).
        const int nrows = BR - 2 * k;
        for (int i = tid; i < nrows * BC4; i += 256) {
            int ro = i / BC4;
            int r  = k + ro;
            int c0 = (i - ro * BC4) * 4;
            int ru = r - 1;                       // r >= 1 always here
            int rd = r + 1;                       // r <= BR-2 always here
            float4 c  = *(const float4*)&S[r][c0];
            float4 up = *(const float4*)&S[ru][c0];
            float4 dn = *(const float4*)&S[rd][c0];
            float  L  = S[r][(c0 == 0)      ? 0        : c0 - 1];
            float  R  = S[r][(c0 == BC - 4) ? (BC - 1) : c0 + 4];
            float4 o;
            o.x = fminf(fminf(fminf(L,   c.x), c.y), fminf(up.x, dn.x));
            o.y = fminf(fminf(fminf(c.x, c.y), c.z), fminf(up.y, dn.y));
            o.z = fminf(fminf(fminf(c.y, c.z), c.w), fminf(up.z, dn.z));
            o.w = fminf(fminf(fminf(c.z, c.w), R),   fminf(up.w, dn.w));
            *(float4*)&Dst[r][c0] = o;
        }
        __syncthreads();

        // dilate(e_k) at center + skel update (skel=0 makes init == update)
        const float (*Ek)[BC] = buf[cur ^ 1];
        const float (*Pv)[BC] = buf[cur];

        float4 hm[6];
        #pragma unroll
        for (int i = 0; i < 6; ++i) {
            int q = min(max(Rr - 1 + i, rLoD), rHiD);   // row-replicate at image edge
            float4 c = *(const float4*)&Ek[q][Cc];
            float  L = Ek[q][Cc - 1];
            float  R = Ek[q][Cc + 4];
            float4 h;
            h.x = fmaxf(fmaxf(L,   c.x), c.y);
            h.y = fmaxf(fmaxf(c.x, c.y), c.z);
            h.z = fmaxf(fmaxf(c.y, c.z), c.w);
            h.w = fmaxf(fmaxf(c.z, c.w), R);
            if (leftE)  h.x = fmaxf(c.x, c.y);          // exclude out-of-image left
            if (rightE) h.w = fmaxf(c.z, c.w);          // exclude out-of-image right
            hm[i] = h;
        }
        #pragma unroll
        for (int i = 0; i < 4; ++i) {
            float4 d;
            d.x = fmaxf(fmaxf(hm[i].x, hm[i+1].x), hm[i+2].x);
            d.y = fmaxf(fmaxf(hm[i].y, hm[i+1].y), hm[i+2].y);
            d.z = fmaxf(fmaxf(hm[i].z, hm[i+1].z), hm[i+2].z);
            d.w = fmaxf(fmaxf(hm[i].w, hm[i+1].w), hm[i+2].w);
            float4 p = *(const float4*)&Pv[Rr + i][Cc];
            float4 dl;
            dl.x = fmaxf(p.x - d.x, 0.f);
            dl.y = fmaxf(p.y - d.y, 0.f);
            dl.z = fmaxf(p.z - d.z, 0.f);
            dl.w = fmaxf(p.w - d.w, 0.f);
            skel[i].x += fmaxf(dl.x - skel[i].x * dl.x, 0.f);
            skel[i].y += fmaxf(dl.y - skel[i].y * dl.y, 0.f);
            skel[i].z += fmaxf(dl.z - skel[i].z * dl.z, 0.f);
            skel[i].w += fmaxf(dl.w - skel[i].w * dl.w, 0.f);
        }
        __syncthreads();
        cur ^= 1;
    }

    // ---- per-tile reduction: one float2 partial per block, no atomics ----
    float sa = 0.f, sb = 0.f;
    #pragma unroll
    for (int i = 0; i < 4; ++i) {
        int gy = y0 + ty * 4 + i;
        int gx = x0 + tx * 4;
        float4 o = *(const float4*)(othp + (size_t)gy * WW + gx);
        sa += (skel[i].x + skel[i].y) + (skel[i].z + skel[i].w);
        sb += skel[i].x * o.x + skel[i].y * o.y + skel[i].z * o.z + skel[i].w * o.w;
    }
    #pragma unroll
    for (int off = 32; off; off >>= 1) {
        sa += __shfl_down(sa, off);
        sb += __shfl_down(sb, off);
    }
    int wid = tid >> 6, lane = tid & 63;
    if (lane == 0) { redA[wid] = sa; redB[wid] = sb; }
    __syncthreads();
    if (tid == 0) {
        float ta = (redA[0] + redA[1]) + (redA[2] + redA[3]);
        float tb = (redB[0] + redB[1]) + (redB[2] + redB[3]);
        int ntile = gridDim.x * gridDim.y;
        int pidx  = chain * ntile + im * gridDim.x + blockIdx.x;
        partials[pidx] = make_float2(tb, ta);   // (.x = sum skel*other, .y = sum skel)
    }
}

__global__ void cldice_final_k(const float2* __restrict__ partials, int ntile,
                               float* __restrict__ out)
{
    double s0 = 0, s1 = 0, s2 = 0, s3 = 0;
    for (int i = threadIdx.x; i < ntile; i += 256) {
        float2 p = partials[i];            // chain 0: skel_pred
        s0 += p.x; s1 += p.y;
        float2 q = partials[ntile + i];    // chain 1: skel_true
        s2 += q.x; s3 += q.y;
    }
    #pragma unroll
    for (int off = 32; off; off >>= 1) {
        s0 += __shfl_down(s0, off);
        s1 += __shfl_down(s1, off);
        s2 += __shfl_down(s2, off);
        s3 += __shfl_down(s3, off);
    }
    __shared__ double sm[4][4];
    int wid = threadIdx.x >> 6, lane = threadIdx.x & 63;
    if (lane == 0) { sm[0][wid] = s0; sm[1][wid] = s1; sm[2][wid] = s2; sm[3][wid] = s3; }
    __syncthreads();
    if (threadIdx.x == 0) {
        double S0 = sm[0][0] + sm[0][1] + sm[0][2] + sm[0][3];
        double S1 = sm[1][0] + sm[1][1] + sm[1][2] + sm[1][3];
        double S2 = sm[2][0] + sm[2][1] + sm[2][2] + sm[2][3];
        double S3 = sm[3][0] + sm[3][1] + sm[3][2] + sm[3][3];
        double tprec = (S0 + 1.0) / (S1 + 1.0);
        double tsens = (S2 + 1.0) / (S3 + 1.0);
        out[0] = (float)(1.0 - 2.0 * (tprec * tsens) / (tprec + tsens));
    }
}

extern "C" void kernel_launch(void* const* d_in, const int* in_sizes, int n_in,
                              void* d_out, int out_size, void* d_ws, size_t ws_size,
                              hipStream_t stream)
{
    const float* y_pred = (const float*)d_in[0];
    const float* y_true = (const float*)d_in[1];
    int B = in_sizes[0] / NPIX;            // 32 images

    float2* partials = (float2*)d_ws;      // 2 * B * 64 float2 = 32 KB for B=32
    dim3 grid(64, B, 2);                   // 8x8 tiles, B images, 2 chains
    cldice_fused_k<<<grid, 256, 0, stream>>>(y_pred, y_true, partials);

    int ntile = 64 * B;
    cldice_final_k<<<1, 256, 0, stream>>>(partials, ntile, (float*)d_out);
}

// Round 8
// 66.402 us; speedup vs baseline: 3.2871x; 1.4748x over previous
//
#include <hip/hip_runtime.h>
#include <hip/hip_fp16.h>
#include <math.h>

#define HH 512
#define WW 512
#define NPIX (HH*WW)

#define TS   64          // output tile
#define BR   74          // buffer rows: 5 + 64 + 5
#define BCP  42          // half2 pairs per row (84 halves); row stride 168 B
#define NQ   21          // 4-half quads per row
#define ROFF 5           // center row offset
#define COFF 8           // center col offset in halves

// ---- packed f16 ops as VOP3P inline asm over unsigned (ROCm header lacks __hmin2/__hmax2) ----
typedef unsigned uh2;
__device__ __forceinline__ uh2 pmin(uh2 a, uh2 b){ uh2 r; asm("v_pk_min_f16 %0, %1, %2" : "=v"(r) : "v"(a), "v"(b)); return r; }
__device__ __forceinline__ uh2 pmax(uh2 a, uh2 b){ uh2 r; asm("v_pk_max_f16 %0, %1, %2" : "=v"(r) : "v"(a), "v"(b)); return r; }
__device__ __forceinline__ uh2 padd(uh2 a, uh2 b){ uh2 r; asm("v_pk_add_f16 %0, %1, %2" : "=v"(r) : "v"(a), "v"(b)); return r; }
// a - b
__device__ __forceinline__ uh2 psub(uh2 a, uh2 b){ uh2 r; asm("v_pk_add_f16 %0, %1, %2 neg_lo:[0,1] neg_hi:[0,1]" : "=v"(r) : "v"(a), "v"(b)); return r; }
// -s*d + d
__device__ __forceinline__ uh2 pnfma(uh2 s, uh2 d){ uh2 r; asm("v_pk_fma_f16 %0, %1, %2, %2 neg_lo:[1,0,0] neg_hi:[1,0,0]" : "=v"(r) : "v"(s), "v"(d)); return r; }
__device__ __forceinline__ uh2 pmin3(uh2 a, uh2 b, uh2 c){ return pmin(pmin(a,b),c); }
__device__ __forceinline__ uh2 pmax3(uh2 a, uh2 b, uh2 c){ return pmax(pmax(a,b),c); }

__device__ __forceinline__ uh2 shifthi(uh2 lo, uh2 hi){ return (lo >> 16) | (hi << 16); }   // (lo.y, hi.x)
__device__ __forceinline__ uh2 duplo(uh2 v){ return (v << 16) | (v & 0xffffu); }
__device__ __forceinline__ uh2 duphi(uh2 v){ return (v >> 16) | (v & 0xffff0000u); }
__device__ __forceinline__ uh2 pk2(float x, float y){
    __half2 h = __halves2half2(__float2half_rn(x), __float2half_rn(y));
    union { __half2 h; uh2 u; } c; c.h = h; return c.u;
}
__device__ __forceinline__ float lo_f(uh2 v){ union { uh2 u; __half2 h; } c; c.u = v; return __low2float(c.h); }
__device__ __forceinline__ float hi_f(uh2 v){ union { uh2 u; __half2 h; } c; c.u = v; return __high2float(c.h); }

// One block = one 64x64 tile of one image of one chain; full soft_skel chain
// in f16 LDS (packed pairs), skel in packed registers, one float2 partial.
__global__ __launch_bounds__(256, 6)
void cldice_fused_k(const float* __restrict__ y_pred,
                    const float* __restrict__ y_true,
                    float2* __restrict__ partials)
{
    __shared__ __align__(16) uh2 buf[2][BR][BCP];
    __shared__ float redA[4], redB[4];

    const int tid   = threadIdx.x;
    const int chain = blockIdx.z;
    const int im    = blockIdx.y;
    const int tileY = blockIdx.x >> 3;
    const int tileX = blockIdx.x & 7;
    const int y0 = tileY * TS;
    const int x0 = tileX * TS;

    const float* __restrict__ imgp = (chain ? y_true : y_pred) + (size_t)im * NPIX;
    const float* __restrict__ othp = (chain ? y_pred : y_true) + (size_t)im * NPIX;

    // ---- stage tile + halo (replicate-clamped) to f16 LDS ----
    for (int i = tid; i < BR * NQ; i += 256) {
        int r = i / NQ;
        int q = i - r * NQ;
        int gy = min(max(y0 - ROFF + r, 0), HH - 1);
        int gx = x0 - COFF + 4 * q;
        const float* rowp = imgp + (size_t)gy * WW;
        float4 v;
        if ((unsigned)gx <= (unsigned)(WW - 4)) {
            v = *(const float4*)(rowp + gx);
        } else {
            int g0 = min(max(gx + 0, 0), WW - 1);
            int g1 = min(max(gx + 1, 0), WW - 1);
            int g2 = min(max(gx + 2, 0), WW - 1);
            int g3 = min(max(gx + 3, 0), WW - 1);
            v.x = rowp[g0]; v.y = rowp[g1]; v.z = rowp[g2]; v.w = rowp[g3];
        }
        uint2 w; w.x = pk2(v.x, v.y); w.y = pk2(v.z, v.w);
        *(uint2*)&buf[0][r][2 * q] = w;
    }
    __syncthreads();

    const int ty = tid >> 4;           // 16x16 threads over 64x64 center
    const int tx = tid & 15;
    const int Rr = ROFF + ty * 4;      // thread's 4 center rows
    const int cp = 4 + 2 * tx;         // thread's center pair index

    const int  rLoD  = (y0 == 0)       ? ROFF            : 0;
    const int  rHiD  = (y0 + TS == HH) ? (ROFF + TS - 1) : (BR - 1);
    const bool leftE  = (x0 == 0)       && (tx == 0);
    const bool rightE = (x0 + TS == WW) && (tx == 15);

    uh2 sk00=0u, sk01=0u, sk10=0u, sk11=0u, sk20=0u, sk21=0u, sk30=0u, sk31=0u;

    int cur = 0;
    #pragma unroll
    for (int stage = 0; stage < 4; ++stage) {
        const int k = stage + 1;                  // erosion depth
        const uh2 (*S)[BCP]   = buf[cur];
        uh2       (*Dst)[BCP] = buf[cur ^ 1];

        // erode rows [k, BR-1-k] (exactly what later consumers read)
        const int nrows = BR - 2 * k;
        for (int i = tid; i < nrows * NQ; i += 256) {
            int ro = i / NQ;
            int r  = k + ro;
            int q  = i - ro * NQ;
            int p  = 2 * q;
            uint2 C  = *(const uint2*)&S[r][p];
            uint2 Up = *(const uint2*)&S[r - 1][p];
            uint2 Dn = *(const uint2*)&S[r + 1][p];
            uh2 Lh = S[r][(q == 0)      ? 0          : p - 1];
            uh2 Rh = S[r][(q == NQ - 1) ? (2*NQ - 1) : p + 2];
            uh2 vm0 = pmin3(C.x, Up.x, Dn.x);
            uh2 vm1 = pmin3(C.y, Up.y, Dn.y);
            uh2 mid = shifthi(C.x, C.y);
            uh2 A0  = (q == 0)      ? duplo(C.x) : shifthi(Lh, C.x);
            uh2 C1  = (q == NQ - 1) ? duphi(C.y) : shifthi(C.y, Rh);
            uint2 O;
            O.x = pmin(vm0, pmin3(A0,  C.x, mid));
            O.y = pmin(vm1, pmin3(mid, C.y, C1));
            *(uint2*)&Dst[r][p] = O;
        }
        __syncthreads();

        // dilate(e_k) at center + skel update (skel=0 makes init == update)
        const uh2 (*Ek)[BCP] = buf[cur ^ 1];
        const uh2 (*Pv)[BCP] = buf[cur];

        uh2 hm0[6], hm1[6];
        #pragma unroll
        for (int i = 0; i < 6; ++i) {
            int q = min(max(Rr - 1 + i, rLoD), rHiD);   // row-replicate at image edge
            uint2 C = *(const uint2*)&Ek[q][cp];
            uh2 Lh = Ek[q][cp - 1];
            uh2 Rh = Ek[q][cp + 2];
            uh2 mid = shifthi(C.x, C.y);
            uh2 A0  = leftE  ? duplo(C.x) : shifthi(Lh, C.x);
            uh2 C1  = rightE ? duphi(C.y) : shifthi(C.y, Rh);
            hm0[i] = pmax3(A0,  C.x, mid);
            hm1[i] = pmax3(mid, C.y, C1);
        }
        #pragma unroll
        for (int i = 0; i < 4; ++i) {
            uh2 d0 = pmax3(hm0[i], hm0[i+1], hm0[i+2]);
            uh2 d1 = pmax3(hm1[i], hm1[i+1], hm1[i+2]);
            uint2 P = *(const uint2*)&Pv[Rr + i][cp];
            uh2 dl0 = pmax(psub(P.x, d0), 0u);
            uh2 dl1 = pmax(psub(P.y, d1), 0u);
            uh2 *s0 = (i==0)? &sk00 : (i==1)? &sk10 : (i==2)? &sk20 : &sk30;
            uh2 *s1 = (i==0)? &sk01 : (i==1)? &sk11 : (i==2)? &sk21 : &sk31;
            *s0 = padd(*s0, pmax(pnfma(*s0, dl0), 0u));
            *s1 = padd(*s1, pmax(pnfma(*s1, dl1), 0u));
        }
        __syncthreads();
        cur ^= 1;
    }

    // ---- per-tile reduction: one float2 partial per block ----
    float sa = 0.f, sb = 0.f;
    #pragma unroll
    for (int i = 0; i < 4; ++i) {
        uh2 v0 = (i==0)? sk00 : (i==1)? sk10 : (i==2)? sk20 : sk30;
        uh2 v1 = (i==0)? sk01 : (i==1)? sk11 : (i==2)? sk21 : sk31;
        int gy = y0 + ty * 4 + i;
        int gx = x0 + tx * 4;
        float4 o = *(const float4*)(othp + (size_t)gy * WW + gx);
        float s0 = lo_f(v0), s1 = hi_f(v0), s2 = lo_f(v1), s3 = hi_f(v1);
        sa += (s0 + s1) + (s2 + s3);
        sb += s0 * o.x + s1 * o.y + s2 * o.z + s3 * o.w;
    }
    #pragma unroll
    for (int off = 32; off; off >>= 1) {
        sa += __shfl_down(sa, off);
        sb += __shfl_down(sb, off);
    }
    int wid = tid >> 6, lane = tid & 63;
    if (lane == 0) { redA[wid] = sa; redB[wid] = sb; }
    __syncthreads();
    if (tid == 0) {
        float ta = (redA[0] + redA[1]) + (redA[2] + redA[3]);
        float tb = (redB[0] + redB[1]) + (redB[2] + redB[3]);
        int ntile = gridDim.x * gridDim.y;
        int pidx  = chain * ntile + im * gridDim.x + blockIdx.x;
        partials[pidx] = make_float2(tb, ta);   // (.x = sum skel*other, .y = sum skel)
    }
}

__global__ void cldice_final_k(const float2* __restrict__ partials, int ntile,
                               float* __restrict__ out)
{
    double s0 = 0, s1 = 0, s2 = 0, s3 = 0;
    for (int i = threadIdx.x; i < ntile; i += 256) {
        float2 p = partials[i];            // chain 0: skel_pred
        s0 += p.x; s1 += p.y;
        float2 q = partials[ntile + i];    // chain 1: skel_true
        s2 += q.x; s3 += q.y;
    }
    #pragma unroll
    for (int off = 32; off; off >>= 1) {
        s0 += __shfl_down(s0, off);
        s1 += __shfl_down(s1, off);
        s2 += __shfl_down(s2, off);
        s3 += __shfl_down(s3, off);
    }
    __shared__ double sm[4][4];
    int wid = threadIdx.x >> 6, lane = threadIdx.x & 63;
    if (lane == 0) { sm[0][wid] = s0; sm[1][wid] = s1; sm[2][wid] = s2; sm[3][wid] = s3; }
    __syncthreads();
    if (threadIdx.x == 0) {
        double S0 = sm[0][0] + sm[0][1] + sm[0][2] + sm[0][3];
        double S1 = sm[1][0] + sm[1][1] + sm[1][2] + sm[1][3];
        double S2 = sm[2][0] + sm[2][1] + sm[2][2] + sm[2][3];
        double S3 = sm[3][0] + sm[3][1] + sm[3][2] + sm[3][3];
        double tprec = (S0 + 1.0) / (S1 + 1.0);
        double tsens = (S2 + 1.0) / (S3 + 1.0);
        out[0] = (float)(1.0 - 2.0 * (tprec * tsens) / (tprec + tsens));
    }
}

extern "C" void kernel_launch(void* const* d_in, const int* in_sizes, int n_in,
                              void* d_out, int out_size, void* d_ws, size_t ws_size,
                              hipStream_t stream)
{
    const float* y_pred = (const float*)d_in[0];
    const float* y_true = (const float*)d_in[1];
    int B = in_sizes[0] / NPIX;            // 32 images

    float2* partials = (float2*)d_ws;      // 2 * B * 64 float2 = 32 KB for B=32
    dim3 grid(64, B, 2);                   // 8x8 tiles, B images, 2 chains
    cldice_fused_k<<<grid, 256, 0, stream>>>(y_pred, y_true, partials);

    int ntile = 64 * B;
    cldice_final_k<<<1, 256, 0, stream>>>(partials, ntile, (float*)d_out);
}

// Round 9
// 60.115 us; speedup vs baseline: 3.6309x; 1.1046x over previous
//
#include <hip/hip_runtime.h>
#include <hip/hip_fp16.h>
#include <math.h>

#define HH 512
#define WW 512
#define NPIX (HH*WW)

#define TS   64          // output tile
#define BR   74          // buffer rows: 5 + 64 + 5
#define BCP  42          // half2 pairs per row (84 halves); row stride 168 B
#define NQ   21          // 4-half quads (uint2) per row
#define ROFF 5           // center row offset
#define COFF 8           // center col offset in halves

// ---- packed f16 ops as VOP3P inline asm over unsigned (ROCm header lacks __hmin2/__hmax2) ----
typedef unsigned uh2;
__device__ __forceinline__ uh2 pmin(uh2 a, uh2 b){ uh2 r; asm("v_pk_min_f16 %0, %1, %2" : "=v"(r) : "v"(a), "v"(b)); return r; }
__device__ __forceinline__ uh2 pmax(uh2 a, uh2 b){ uh2 r; asm("v_pk_max_f16 %0, %1, %2" : "=v"(r) : "v"(a), "v"(b)); return r; }
__device__ __forceinline__ uh2 padd(uh2 a, uh2 b){ uh2 r; asm("v_pk_add_f16 %0, %1, %2" : "=v"(r) : "v"(a), "v"(b)); return r; }
// a - b
__device__ __forceinline__ uh2 psub(uh2 a, uh2 b){ uh2 r; asm("v_pk_add_f16 %0, %1, %2 neg_lo:[0,1] neg_hi:[0,1]" : "=v"(r) : "v"(a), "v"(b)); return r; }
// -s*d + d
__device__ __forceinline__ uh2 pnfma(uh2 s, uh2 d){ uh2 r; asm("v_pk_fma_f16 %0, %1, %2, %2 neg_lo:[1,0,0] neg_hi:[1,0,0]" : "=v"(r) : "v"(s), "v"(d)); return r; }
__device__ __forceinline__ uh2 pmin3(uh2 a, uh2 b, uh2 c){ return pmin(pmin(a,b),c); }
__device__ __forceinline__ uh2 pmax3(uh2 a, uh2 b, uh2 c){ return pmax(pmax(a,b),c); }

__device__ __forceinline__ uh2 shifthi(uh2 lo, uh2 hi){ return (lo >> 16) | (hi << 16); }   // (lo.y, hi.x)
__device__ __forceinline__ uh2 duplo(uh2 v){ return (v << 16) | (v & 0xffffu); }
__device__ __forceinline__ uh2 duphi(uh2 v){ return (v >> 16) | (v & 0xffff0000u); }
__device__ __forceinline__ uh2 pk2(float x, float y){
    __half2 h = __halves2half2(__float2half_rn(x), __float2half_rn(y));
    union { __half2 h; uh2 u; } c; c.h = h; return c.u;
}
__device__ __forceinline__ float lo_f(uh2 v){ union { uh2 u; __half2 h; } c; c.u = v; return __low2float(c.h); }
__device__ __forceinline__ float hi_f(uh2 v){ union { uh2 u; __half2 h; } c; c.u = v; return __high2float(c.h); }

// One block = one 64x64 tile of one image of one chain; full soft_skel chain
// in f16 LDS (packed pairs), skel in packed registers, one float2 partial.
__global__ __launch_bounds__(256, 6)
void cldice_fused_k(const float* __restrict__ y_pred,
                    const float* __restrict__ y_true,
                    float2* __restrict__ partials)
{
    __shared__ __align__(16) uh2 buf[2][BR][BCP];
    __shared__ float redA[4], redB[4];

    const int tid   = threadIdx.x;
    const int chain = blockIdx.z;
    const int im    = blockIdx.y;
    const int tileY = blockIdx.x >> 3;
    const int tileX = blockIdx.x & 7;
    const int y0 = tileY * TS;
    const int x0 = tileX * TS;

    const float* __restrict__ imgp = (chain ? y_true : y_pred) + (size_t)im * NPIX;
    const float* __restrict__ othp = (chain ? y_pred : y_true) + (size_t)im * NPIX;

    // fixed thread -> (row-offset, quad) map: no division inside loops,
    // edge handling becomes per-thread constants (hoisted out of all passes)
    const int  Q    = tid % NQ;        // quad index 0..20
    const int  R0   = tid / NQ;        // 0..12 (R0==12 -> idle lane in strip loops)
    const bool rowAct = (R0 < 12);
    const bool qlo  = (Q == 0);
    const bool qhi  = (Q == NQ - 1);
    const int  pC   = 2 * Q;                 // own pair index
    const int  pL   = qlo ? 0 : pC - 1;      // safe load index (value unused when qlo)
    const int  pR   = qhi ? (BCP - 1) : pC + 2;

    // ---- stage tile + halo (replicate-clamped) to f16 LDS: 7 passes of 12 rows ----
    #pragma unroll
    for (int p = 0; p < 7; ++p) {
        int r = p * 12 + R0;
        if (rowAct && r < BR) {
            int gy = min(max(y0 - ROFF + r, 0), HH - 1);
            int gx = x0 - COFF + 4 * Q;
            const float* rowp = imgp + (size_t)gy * WW;
            float4 v;
            if ((unsigned)gx <= (unsigned)(WW - 4)) {
                v = *(const float4*)(rowp + gx);
            } else {
                int g0 = min(max(gx + 0, 0), WW - 1);
                int g1 = min(max(gx + 1, 0), WW - 1);
                int g2 = min(max(gx + 2, 0), WW - 1);
                int g3 = min(max(gx + 3, 0), WW - 1);
                v.x = rowp[g0]; v.y = rowp[g1]; v.z = rowp[g2]; v.w = rowp[g3];
            }
            uint2 w; w.x = pk2(v.x, v.y); w.y = pk2(v.z, v.w);
            *(uint2*)&buf[0][r][pC] = w;
        }
    }
    __syncthreads();

    const int ty = tid >> 4;           // 16x16 threads over 64x64 center
    const int tx = tid & 15;
    const int Rr = ROFF + ty * 4;      // thread's 4 center rows
    const int cp = 4 + 2 * tx;         // thread's center pair index

    const int  rLoD  = (y0 == 0)       ? ROFF            : 0;
    const int  rHiD  = (y0 + TS == HH) ? (ROFF + TS - 1) : (BR - 1);
    const bool leftE  = (x0 == 0)       && (tx == 0);
    const bool rightE = (x0 + TS == WW) && (tx == 15);

    uh2 sk00=0u, sk01=0u, sk10=0u, sk11=0u, sk20=0u, sk21=0u, sk30=0u, sk31=0u;

    int cur = 0;
    #pragma unroll
    for (int stage = 0; stage < 4; ++stage) {
        const int k = stage + 1;                  // erosion depth
        const uh2 (*S)[BCP]   = buf[cur];
        uh2       (*Dst)[BCP] = buf[cur ^ 1];

        // erode rows [k, BR-1-k]: 6 statically-unrolled passes of 12 rows
        #pragma unroll
        for (int p = 0; p < 6; ++p) {
            int r = k + p * 12 + R0;
            if (rowAct && r <= BR - 1 - k) {
                uint2 C  = *(const uint2*)&S[r][pC];
                uint2 Up = *(const uint2*)&S[r - 1][pC];
                uint2 Dn = *(const uint2*)&S[r + 1][pC];
                uh2 Lh = S[r][pL];
                uh2 Rh = S[r][pR];
                uh2 vm0 = pmin3(C.x, Up.x, Dn.x);
                uh2 vm1 = pmin3(C.y, Up.y, Dn.y);
                uh2 mid = shifthi(C.x, C.y);
                uh2 A0  = qlo ? duplo(C.x) : shifthi(Lh, C.x);
                uh2 C1  = qhi ? duphi(C.y) : shifthi(C.y, Rh);
                uint2 O;
                O.x = pmin(vm0, pmin(A0, mid));   // center already in vm
                O.y = pmin(vm1, pmin(mid, C1));
                *(uint2*)&Dst[r][pC] = O;
            }
        }
        __syncthreads();

        // dilate(e_k) at center + skel update (skel=0 makes init == update)
        const uh2 (*Ek)[BCP] = buf[cur ^ 1];
        const uh2 (*Pv)[BCP] = buf[cur];

        uh2 hm0[6], hm1[6];
        #pragma unroll
        for (int i = 0; i < 6; ++i) {
            int q = min(max(Rr - 1 + i, rLoD), rHiD);   // row-replicate at image edge
            uint2 C = *(const uint2*)&Ek[q][cp];
            uh2 Lh = Ek[q][cp - 1];
            uh2 Rh = Ek[q][cp + 2];
            uh2 mid = shifthi(C.x, C.y);
            uh2 A0  = leftE  ? duplo(C.x) : shifthi(Lh, C.x);
            uh2 C1  = rightE ? duphi(C.y) : shifthi(C.y, Rh);
            hm0[i] = pmax3(A0,  C.x, mid);
            hm1[i] = pmax3(mid, C.y, C1);
        }
        #pragma unroll
        for (int i = 0; i < 4; ++i) {
            uh2 d0 = pmax3(hm0[i], hm0[i+1], hm0[i+2]);
            uh2 d1 = pmax3(hm1[i], hm1[i+1], hm1[i+2]);
            uint2 P = *(const uint2*)&Pv[Rr + i][cp];
            uh2 dl0 = pmax(psub(P.x, d0), 0u);
            uh2 dl1 = pmax(psub(P.y, d1), 0u);
            uh2 *s0 = (i==0)? &sk00 : (i==1)? &sk10 : (i==2)? &sk20 : &sk30;
            uh2 *s1 = (i==0)? &sk01 : (i==1)? &sk11 : (i==2)? &sk21 : &sk31;
            *s0 = padd(*s0, pmax(pnfma(*s0, dl0), 0u));
            *s1 = padd(*s1, pmax(pnfma(*s1, dl1), 0u));
        }
        __syncthreads();
        cur ^= 1;
    }

    // ---- per-tile reduction: one float2 partial per block ----
    float sa = 0.f, sb = 0.f;
    #pragma unroll
    for (int i = 0; i < 4; ++i) {
        uh2 v0 = (i==0)? sk00 : (i==1)? sk10 : (i==2)? sk20 : sk30;
        uh2 v1 = (i==0)? sk01 : (i==1)? sk11 : (i==2)? sk21 : sk31;
        int gy = y0 + ty * 4 + i;
        int gx = x0 + tx * 4;
        float4 o = *(const float4*)(othp + (size_t)gy * WW + gx);
        float s0 = lo_f(v0), s1 = hi_f(v0), s2 = lo_f(v1), s3 = hi_f(v1);
        sa += (s0 + s1) + (s2 + s3);
        sb += s0 * o.x + s1 * o.y + s2 * o.z + s3 * o.w;
    }
    #pragma unroll
    for (int off = 32; off; off >>= 1) {
        sa += __shfl_down(sa, off);
        sb += __shfl_down(sb, off);
    }
    int wid = tid >> 6, lane = tid & 63;
    if (lane == 0) { redA[wid] = sa; redB[wid] = sb; }
    __syncthreads();
    if (tid == 0) {
        float ta = (redA[0] + redA[1]) + (redA[2] + redA[3]);
        float tb = (redB[0] + redB[1]) + (redB[2] + redB[3]);
        int ntile = gridDim.x * gridDim.y;
        int pidx  = chain * ntile + im * gridDim.x + blockIdx.x;
        partials[pidx] = make_float2(tb, ta);   // (.x = sum skel*other, .y = sum skel)
    }
}

__global__ void cldice_final_k(const float2* __restrict__ partials, int ntile,
                               float* __restrict__ out)
{
    double s0 = 0, s1 = 0, s2 = 0, s3 = 0;
    for (int i = threadIdx.x; i < ntile; i += 256) {
        float2 p = partials[i];            // chain 0: skel_pred
        s0 += p.x; s1 += p.y;
        float2 q = partials[ntile + i];    // chain 1: skel_true
        s2 += q.x; s3 += q.y;
    }
    #pragma unroll
    for (int off = 32; off; off >>= 1) {
        s0 += __shfl_down(s0, off);
        s1 += __shfl_down(s1, off);
        s2 += __shfl_down(s2, off);
        s3 += __shfl_down(s3, off);
    }
    __shared__ double sm[4][4];
    int wid = threadIdx.x >> 6, lane = threadIdx.x & 63;
    if (lane == 0) { sm[0][wid] = s0; sm[1][wid] = s1; sm[2][wid] = s2; sm[3][wid] = s3; }
    __syncthreads();
    if (threadIdx.x == 0) {
        double S0 = sm[0][0] + sm[0][1] + sm[0][2] + sm[0][3];
        double S1 = sm[1][0] + sm[1][1] + sm[1][2] + sm[1][3];
        double S2 = sm[2][0] + sm[2][1] + sm[2][2] + sm[2][3];
        double S3 = sm[3][0] + sm[3][1] + sm[3][2] + sm[3][3];
        double tprec = (S0 + 1.0) / (S1 + 1.0);
        double tsens = (S2 + 1.0) / (S3 + 1.0);
        out[0] = (float)(1.0 - 2.0 * (tprec * tsens) / (tprec + tsens));
    }
}

extern "C" void kernel_launch(void* const* d_in, const int* in_sizes, int n_in,
                              void* d_out, int out_size, void* d_ws, size_t ws_size,
                              hipStream_t stream)
{
    const float* y_pred = (const float*)d_in[0];
    const float* y_true = (const float*)d_in[1];
    int B = in_sizes[0] / NPIX;            // 32 images

    float2* partials = (float2*)d_ws;      // 2 * B * 64 float2 = 32 KB for B=32
    dim3 grid(64, B, 2);                   // 8x8 tiles, B images, 2 chains
    cldice_fused_k<<<grid, 256, 0, stream>>>(y_pred, y_true, partials);

    int ntile = 64 * B;
    cldice_final_k<<<1, 256, 0, stream>>>(partials, ntile, (float*)d_out);
}

// Round 10
// 59.953 us; speedup vs baseline: 3.6407x; 1.0027x over previous
//
#include <hip/hip_runtime.h>
#include <hip/hip_fp16.h>
#include <math.h>

#define HH 512
#define WW 512
#define NPIX (HH*WW)

#define TS   64          // output tile
#define BR   74          // buffer rows: 5 + 64 + 5
#define BCP  42          // half2 pairs per row (84 halves); row stride 168 B
#define NQ   21          // 4-half quads (uint2) per row
#define ROFF 5           // center row offset
#define COFF 8           // center col offset in halves

// ---- packed f16 ops as VOP3P inline asm over unsigned (ROCm header lacks __hmin2/__hmax2) ----
typedef unsigned uh2;
__device__ __forceinline__ uh2 pmin(uh2 a, uh2 b){ uh2 r; asm("v_pk_min_f16 %0, %1, %2" : "=v"(r) : "v"(a), "v"(b)); return r; }
__device__ __forceinline__ uh2 pmax(uh2 a, uh2 b){ uh2 r; asm("v_pk_max_f16 %0, %1, %2" : "=v"(r) : "v"(a), "v"(b)); return r; }
__device__ __forceinline__ uh2 padd(uh2 a, uh2 b){ uh2 r; asm("v_pk_add_f16 %0, %1, %2" : "=v"(r) : "v"(a), "v"(b)); return r; }
// a - b
__device__ __forceinline__ uh2 psub(uh2 a, uh2 b){ uh2 r; asm("v_pk_add_f16 %0, %1, %2 neg_lo:[0,1] neg_hi:[0,1]" : "=v"(r) : "v"(a), "v"(b)); return r; }
// -s*d + d
__device__ __forceinline__ uh2 pnfma(uh2 s, uh2 d){ uh2 r; asm("v_pk_fma_f16 %0, %1, %2, %2 neg_lo:[1,0,0] neg_hi:[1,0,0]" : "=v"(r) : "v"(s), "v"(d)); return r; }
__device__ __forceinline__ uh2 pmin3(uh2 a, uh2 b, uh2 c){ return pmin(pmin(a,b),c); }
__device__ __forceinline__ uh2 pmax3(uh2 a, uh2 b, uh2 c){ return pmax(pmax(a,b),c); }

__device__ __forceinline__ uh2 shifthi(uh2 lo, uh2 hi){ return (lo >> 16) | (hi << 16); }   // (lo.y, hi.x)
__device__ __forceinline__ uh2 duplo(uh2 v){ return (v << 16) | (v & 0xffffu); }
__device__ __forceinline__ uh2 duphi(uh2 v){ return (v >> 16) | (v & 0xffff0000u); }
__device__ __forceinline__ uh2 pk2(float x, float y){
    __half2 h = __halves2half2(__float2half_rn(x), __float2half_rn(y));
    union { __half2 h; uh2 u; } c; c.h = h; return c.u;
}
__device__ __forceinline__ float lo_f(uh2 v){ union { uh2 u; __half2 h; } c; c.u = v; return __low2float(c.h); }
__device__ __forceinline__ float hi_f(uh2 v){ union { uh2 u; __half2 h; } c; c.u = v; return __high2float(c.h); }

// erode strip: 6 statically-unrolled passes of 12 rows, rows [K, BR-1-K]
#define ERODE(Sb, Db, K) do {                                                  \
    _Pragma("unroll")                                                          \
    for (int p_ = 0; p_ < 6; ++p_) {                                           \
        int r_ = (K) + p_ * 12 + R0;                                           \
        if (rowAct && r_ <= BR - 1 - (K)) {                                    \
            uint2 C  = *(const uint2*)&Sb[r_][pC];                             \
            uint2 Up = *(const uint2*)&Sb[r_ - 1][pC];                         \
            uint2 Dn = *(const uint2*)&Sb[r_ + 1][pC];                         \
            uh2 Lh = Sb[r_][pL];                                               \
            uh2 Rh = Sb[r_][pR];                                               \
            uh2 vm0 = pmin3(C.x, Up.x, Dn.x);                                  \
            uh2 vm1 = pmin3(C.y, Up.y, Dn.y);                                  \
            uh2 mid = shifthi(C.x, C.y);                                       \
            uh2 A0  = qlo ? duplo(C.x) : shifthi(Lh, C.x);                     \
            uh2 C1  = qhi ? duphi(C.y) : shifthi(C.y, Rh);                     \
            uint2 O;                                                           \
            O.x = pmin(vm0, pmin(A0, mid));                                    \
            O.y = pmin(vm1, pmin(mid, C1));                                    \
            *(uint2*)&Db[r_][pC] = O;                                          \
        }                                                                      \
    }                                                                          \
} while (0)

// load e_{k-1} center rows into registers (for next phase's dilate)
#define LOADP(Sb, Pa, Pb, Pc, Pd) do {                                         \
    Pa = *(const uint2*)&Sb[Rr + 0][cp];                                       \
    Pb = *(const uint2*)&Sb[Rr + 1][cp];                                       \
    Pc = *(const uint2*)&Sb[Rr + 2][cp];                                       \
    Pd = *(const uint2*)&Sb[Rr + 3][cp];                                       \
} while (0)

// dilate(e_k) at center (Eb) + skel update with P = e_{k-1} center (registers)
#define DILUPD(Eb, Pa, Pb, Pc, Pd) do {                                        \
    uh2 hm0[6], hm1[6];                                                        \
    _Pragma("unroll")                                                          \
    for (int i_ = 0; i_ < 6; ++i_) {                                           \
        int q_ = min(max(Rr - 1 + i_, rLoD), rHiD);                            \
        uint2 C = *(const uint2*)&Eb[q_][cp];                                  \
        uh2 Lh = Eb[q_][cp - 1];                                               \
        uh2 Rh = Eb[q_][cp + 2];                                               \
        uh2 mid = shifthi(C.x, C.y);                                           \
        uh2 A0  = leftE  ? duplo(C.x) : shifthi(Lh, C.x);                      \
        uh2 C1  = rightE ? duphi(C.y) : shifthi(C.y, Rh);                      \
        hm0[i_] = pmax3(A0,  C.x, mid);                                        \
        hm1[i_] = pmax3(mid, C.y, C1);                                         \
    }                                                                          \
    { uh2 d0 = pmax3(hm0[0], hm0[1], hm0[2]);                                  \
      uh2 d1 = pmax3(hm1[0], hm1[1], hm1[2]);                                  \
      uh2 dl0 = pmax(psub(Pa.x, d0), 0u);                                      \
      uh2 dl1 = pmax(psub(Pa.y, d1), 0u);                                      \
      sk00 = padd(sk00, pmax(pnfma(sk00, dl0), 0u));                           \
      sk01 = padd(sk01, pmax(pnfma(sk01, dl1), 0u)); }                         \
    { uh2 d0 = pmax3(hm0[1], hm0[2], hm0[3]);                                  \
      uh2 d1 = pmax3(hm1[1], hm1[2], hm1[3]);                                  \
      uh2 dl0 = pmax(psub(Pb.x, d0), 0u);                                      \
      uh2 dl1 = pmax(psub(Pb.y, d1), 0u);                                      \
      sk10 = padd(sk10, pmax(pnfma(sk10, dl0), 0u));                           \
      sk11 = padd(sk11, pmax(pnfma(sk11, dl1), 0u)); }                         \
    { uh2 d0 = pmax3(hm0[2], hm0[3], hm0[4]);                                  \
      uh2 d1 = pmax3(hm1[2], hm1[3], hm1[4]);                                  \
      uh2 dl0 = pmax(psub(Pc.x, d0), 0u);                                      \
      uh2 dl1 = pmax(psub(Pc.y, d1), 0u);                                      \
      sk20 = padd(sk20, pmax(pnfma(sk20, dl0), 0u));                           \
      sk21 = padd(sk21, pmax(pnfma(sk21, dl1), 0u)); }                         \
    { uh2 d0 = pmax3(hm0[3], hm0[4], hm0[5]);                                  \
      uh2 d1 = pmax3(hm1[3], hm1[4], hm1[5]);                                  \
      uh2 dl0 = pmax(psub(Pd.x, d0), 0u);                                      \
      uh2 dl1 = pmax(psub(Pd.y, d1), 0u);                                      \
      sk30 = padd(sk30, pmax(pnfma(sk30, dl0), 0u));                           \
      sk31 = padd(sk31, pmax(pnfma(sk31, dl1), 0u)); }                         \
} while (0)

// One block = one 64x64 tile; phases merged: erode(k+1) co-scheduled with
// dilate(k) (both read e_k; e_{k-1} center pre-hoisted to registers).
// 5 barriers instead of 9; two independent streams per phase for ILP.
__global__ __launch_bounds__(256, 6)
void cldice_fused_k(const float* __restrict__ y_pred,
                    const float* __restrict__ y_true,
                    float2* __restrict__ partials)
{
    __shared__ __align__(16) uh2 buf0[BR][BCP];
    __shared__ __align__(16) uh2 buf1[BR][BCP];
    __shared__ float redA[4], redB[4];

    const int tid   = threadIdx.x;
    const int chain = blockIdx.z;
    const int im    = blockIdx.y;
    const int tileY = blockIdx.x >> 3;
    const int tileX = blockIdx.x & 7;
    const int y0 = tileY * TS;
    const int x0 = tileX * TS;

    const float* __restrict__ imgp = (chain ? y_true : y_pred) + (size_t)im * NPIX;
    const float* __restrict__ othp = (chain ? y_pred : y_true) + (size_t)im * NPIX;

    // fixed thread -> (row-offset, quad) map for strip phases
    const int  Q    = tid % NQ;
    const int  R0   = tid / NQ;
    const bool rowAct = (R0 < 12);
    const bool qlo  = (Q == 0);
    const bool qhi  = (Q == NQ - 1);
    const int  pC   = 2 * Q;
    const int  pL   = qlo ? 0 : pC - 1;
    const int  pR   = qhi ? (BCP - 1) : pC + 2;

    // ---- stage tile + halo (replicate-clamped) to f16 LDS ----
    #pragma unroll
    for (int p = 0; p < 7; ++p) {
        int r = p * 12 + R0;
        if (rowAct && r < BR) {
            int gy = min(max(y0 - ROFF + r, 0), HH - 1);
            int gx = x0 - COFF + 4 * Q;
            const float* rowp = imgp + (size_t)gy * WW;
            float4 v;
            if ((unsigned)gx <= (unsigned)(WW - 4)) {
                v = *(const float4*)(rowp + gx);
            } else {
                int g0 = min(max(gx + 0, 0), WW - 1);
                int g1 = min(max(gx + 1, 0), WW - 1);
                int g2 = min(max(gx + 2, 0), WW - 1);
                int g3 = min(max(gx + 3, 0), WW - 1);
                v.x = rowp[g0]; v.y = rowp[g1]; v.z = rowp[g2]; v.w = rowp[g3];
            }
            uint2 w; w.x = pk2(v.x, v.y); w.y = pk2(v.z, v.w);
            *(uint2*)&buf0[r][pC] = w;
        }
    }
    __syncthreads();

    const int ty = tid >> 4;
    const int tx = tid & 15;
    const int Rr = ROFF + ty * 4;
    const int cp = 4 + 2 * tx;

    const int  rLoD  = (y0 == 0)       ? ROFF            : 0;
    const int  rHiD  = (y0 + TS == HH) ? (ROFF + TS - 1) : (BR - 1);
    const bool leftE  = (x0 == 0)       && (tx == 0);
    const bool rightE = (x0 + TS == WW) && (tx == 15);

    uh2 sk00=0u, sk01=0u, sk10=0u, sk11=0u, sk20=0u, sk21=0u, sk30=0u, sk31=0u;
    uint2 P0, P1, P2, P3, N0, N1, N2, N3;

    // A1: erode1 (buf0->buf1); hoist img center rows
    ERODE(buf0, buf1, 1);
    LOADP(buf0, P0, P1, P2, P3);
    __syncthreads();

    // A2: erode2 (buf1->buf0) + dilate1 (buf1, P=img) ; hoist e1 center
    ERODE(buf1, buf0, 2);
    LOADP(buf1, N0, N1, N2, N3);
    DILUPD(buf1, P0, P1, P2, P3);
    __syncthreads();

    // A3: erode3 (buf0->buf1) + dilate2 (buf0, P=e1) ; hoist e2 center
    ERODE(buf0, buf1, 3);
    LOADP(buf0, P0, P1, P2, P3);
    DILUPD(buf0, N0, N1, N2, N3);
    __syncthreads();

    // A4: erode4 (buf1->buf0) + dilate3 (buf1, P=e2) ; hoist e3 center
    ERODE(buf1, buf0, 4);
    LOADP(buf1, N0, N1, N2, N3);
    DILUPD(buf1, P0, P1, P2, P3);
    __syncthreads();

    // A5: dilate4 (buf0, P=e3) + reduction
    DILUPD(buf0, N0, N1, N2, N3);

    float sa = 0.f, sb = 0.f;
    #pragma unroll
    for (int i = 0; i < 4; ++i) {
        uh2 v0 = (i==0)? sk00 : (i==1)? sk10 : (i==2)? sk20 : sk30;
        uh2 v1 = (i==0)? sk01 : (i==1)? sk11 : (i==2)? sk21 : sk31;
        int gy = y0 + ty * 4 + i;
        int gx = x0 + tx * 4;
        float4 o = *(const float4*)(othp + (size_t)gy * WW + gx);
        float s0 = lo_f(v0), s1 = hi_f(v0), s2 = lo_f(v1), s3 = hi_f(v1);
        sa += (s0 + s1) + (s2 + s3);
        sb += s0 * o.x + s1 * o.y + s2 * o.z + s3 * o.w;
    }
    #pragma unroll
    for (int off = 32; off; off >>= 1) {
        sa += __shfl_down(sa, off);
        sb += __shfl_down(sb, off);
    }
    int wid = tid >> 6, lane = tid & 63;
    if (lane == 0) { redA[wid] = sa; redB[wid] = sb; }
    __syncthreads();
    if (tid == 0) {
        float ta = (redA[0] + redA[1]) + (redA[2] + redA[3]);
        float tb = (redB[0] + redB[1]) + (redB[2] + redB[3]);
        int ntile = gridDim.x * gridDim.y;
        int pidx  = chain * ntile + im * gridDim.x + blockIdx.x;
        partials[pidx] = make_float2(tb, ta);   // (.x = sum skel*other, .y = sum skel)
    }
}

__global__ void cldice_final_k(const float2* __restrict__ partials, int ntile,
                               float* __restrict__ out)
{
    double s0 = 0, s1 = 0, s2 = 0, s3 = 0;
    for (int i = threadIdx.x; i < ntile; i += 256) {
        float2 p = partials[i];            // chain 0: skel_pred
        s0 += p.x; s1 += p.y;
        float2 q = partials[ntile + i];    // chain 1: skel_true
        s2 += q.x; s3 += q.y;
    }
    #pragma unroll
    for (int off = 32; off; off >>= 1) {
        s0 += __shfl_down(s0, off);
        s1 += __shfl_down(s1, off);
        s2 += __shfl_down(s2, off);
        s3 += __shfl_down(s3, off);
    }
    __shared__ double sm[4][4];
    int wid = threadIdx.x >> 6, lane = threadIdx.x & 63;
    if (lane == 0) { sm[0][wid] = s0; sm[1][wid] = s1; sm[2][wid] = s2; sm[3][wid] = s3; }
    __syncthreads();
    if (threadIdx.x == 0) {
        double S0 = sm[0][0] + sm[0][1] + sm[0][2] + sm[0][3];
        double S1 = sm[1][0] + sm[1][1] + sm[1][2] + sm[1][3];
        double S2 = sm[2][0] + sm[2][1] + sm[2][2] + sm[2][3];
        double S3 = sm[3][0] + sm[3][1] + sm[3][2] + sm[3][3];
        double tprec = (S0 + 1.0) / (S1 + 1.0);
        double tsens = (S2 + 1.0) / (S3 + 1.0);
        out[0] = (float)(1.0 - 2.0 * (tprec * tsens) / (tprec + tsens));
    }
}

extern "C" void kernel_launch(void* const* d_in, const int* in_sizes, int n_in,
                              void* d_out, int out_size, void* d_ws, size_t ws_size,
                              hipStream_t stream)
{
    const float* y_pred = (const float*)d_in[0];
    const float* y_true = (const float*)d_in[1];
    int B = in_sizes[0] / NPIX;            // 32 images

    float2* partials = (float2*)d_ws;      // 2 * B * 64 float2 = 32 KB for B=32
    dim3 grid(64, B, 2);                   // 8x8 tiles, B images, 2 chains
    cldice_fused_k<<<grid, 256, 0, stream>>>(y_pred, y_true, partials);

    int ntile = 64 * B;
    cldice_final_k<<<1, 256, 0, stream>>>(partials, ntile, (float*)d_out);
}

// Round 11
// 55.213 us; speedup vs baseline: 3.9533x; 1.0859x over previous
//
#include <hip/hip_runtime.h>
#include <hip/hip_fp16.h>

#define HH 512
#define WW 512
#define NPIX (HH*WW)
#define NBANDS 32
#define BAND (HH/NBANDS)     // 16 output rows per wave
#define NS 28                // ceil((BAND+10)/4)*4 streamed steps
#define PINF2 0x7C007C00u    // packed f16 +inf
#define NINF2 0xFC00FC00u    // packed f16 -inf

// ---- packed f16 ops as VOP3P inline asm (proven in rounds 8-10) ----
typedef unsigned uh2;
__device__ __forceinline__ uh2 pmin(uh2 a, uh2 b){ uh2 r; asm("v_pk_min_f16 %0, %1, %2" : "=v"(r) : "v"(a), "v"(b)); return r; }
__device__ __forceinline__ uh2 pmax(uh2 a, uh2 b){ uh2 r; asm("v_pk_max_f16 %0, %1, %2" : "=v"(r) : "v"(a), "v"(b)); return r; }
__device__ __forceinline__ uh2 padd(uh2 a, uh2 b){ uh2 r; asm("v_pk_add_f16 %0, %1, %2" : "=v"(r) : "v"(a), "v"(b)); return r; }
__device__ __forceinline__ uh2 psub(uh2 a, uh2 b){ uh2 r; asm("v_pk_add_f16 %0, %1, %2 neg_lo:[0,1] neg_hi:[0,1]" : "=v"(r) : "v"(a), "v"(b)); return r; }
__device__ __forceinline__ uh2 pnfma(uh2 s, uh2 d){ uh2 r; asm("v_pk_fma_f16 %0, %1, %2, %2 neg_lo:[1,0,0] neg_hi:[1,0,0]" : "=v"(r) : "v"(s), "v"(d)); return r; }
__device__ __forceinline__ uh2 pmin3(uh2 a, uh2 b, uh2 c){ return pmin(pmin(a,b),c); }
__device__ __forceinline__ uh2 pmax3(uh2 a, uh2 b, uh2 c){ return pmax(pmax(a,b),c); }
__device__ __forceinline__ uh2 alignh(uh2 lo, uh2 hi){ return (lo >> 16) | (hi << 16); }   // (lo.y, hi.x)
__device__ __forceinline__ uh2 pk2(float x, float y){
    __half2 h = __halves2half2(__float2half_rn(x), __float2half_rn(y));
    union { __half2 h; uh2 u; } c; c.h = h; return c.u;
}
__device__ __forceinline__ float lo_f(uh2 v){ union { uh2 u; __half2 h; } c; c.u = v; return __low2float(c.h); }
__device__ __forceinline__ float hi_f(uh2 v){ union { uh2 u; __half2 h; } c; c.u = v; return __high2float(c.h); }

// one full 512-wide row: lane l holds halves [8l .. 8l+7] in 4 packed regs
struct R4 { uh2 a, b, c, d; };
__device__ __forceinline__ R4 r4splat(uh2 v){ R4 r; r.a=v; r.b=v; r.c=v; r.d=v; return r; }
__device__ __forceinline__ R4 ldrow(const float* p){
    float4 u = *(const float4*)p;
    float4 v = *(const float4*)(p + 4);
    R4 r; r.a = pk2(u.x,u.y); r.b = pk2(u.z,u.w); r.c = pk2(v.x,v.y); r.d = pk2(v.z,v.w);
    return r;
}
__device__ __forceinline__ R4 vmin3(const R4& x, const R4& y, const R4& z){
    R4 r; r.a=pmin3(x.a,y.a,z.a); r.b=pmin3(x.b,y.b,z.b); r.c=pmin3(x.c,y.c,z.c); r.d=pmin3(x.d,y.d,z.d); return r;
}
__device__ __forceinline__ R4 rmin(const R4& x, const R4& y){
    R4 r; r.a=pmin(x.a,y.a); r.b=pmin(x.b,y.b); r.c=pmin(x.c,y.c); r.d=pmin(x.d,y.d); return r;
}
__device__ __forceinline__ R4 rmax3(const R4& x, const R4& y, const R4& z){
    R4 r; r.a=pmax3(x.a,y.a,z.a); r.b=pmax3(x.b,y.b,z.b); r.c=pmax3(x.c,y.c,z.c); r.d=pmax3(x.d,y.d,z.d); return r;
}
__device__ __forceinline__ R4 relusub(const R4& p, const R4& d){
    R4 r; r.a=pmax(psub(p.a,d.a),0u); r.b=pmax(psub(p.b,d.b),0u);
          r.c=pmax(psub(p.c,d.c),0u); r.d=pmax(psub(p.d,d.d),0u); return r;
}
__device__ __forceinline__ void skupd(R4& s, const R4& d){
    s.a = padd(s.a, pmax(pnfma(s.a,d.a),0u));
    s.b = padd(s.b, pmax(pnfma(s.b,d.b),0u));
    s.c = padd(s.c, pmax(pnfma(s.c,d.c),0u));
    s.d = padd(s.d, pmax(pnfma(s.d,d.d),0u));
}
// horizontal 3-window min/max across the wave-held row; neighbor halves via
// ds_bpermute with precomputed lane addrs; image edges -> neutral
__device__ __forceinline__ R4 hmin3w(const R4& x, int upA, int dnA, bool l0, bool l63){
    uh2 L  = (uh2)__builtin_amdgcn_ds_bpermute(upA, (int)x.d); L  = l0  ? PINF2 : L;
    uh2 Rv = (uh2)__builtin_amdgcn_ds_bpermute(dnA, (int)x.a); Rv = l63 ? PINF2 : Rv;
    uh2 s0=alignh(L,x.a), s1=alignh(x.a,x.b), s2=alignh(x.b,x.c), s3=alignh(x.c,x.d), s4=alignh(x.d,Rv);
    R4 m; m.a=pmin3(s0,x.a,s1); m.b=pmin3(s1,x.b,s2); m.c=pmin3(s2,x.c,s3); m.d=pmin3(s3,x.d,s4);
    return m;
}
__device__ __forceinline__ R4 hmax3w(const R4& x, int upA, int dnA, bool l0, bool l63){
    uh2 L  = (uh2)__builtin_amdgcn_ds_bpermute(upA, (int)x.d); L  = l0  ? NINF2 : L;
    uh2 Rv = (uh2)__builtin_amdgcn_ds_bpermute(dnA, (int)x.a); Rv = l63 ? NINF2 : Rv;
    uh2 s0=alignh(L,x.a), s1=alignh(x.a,x.b), s2=alignh(x.b,x.c), s3=alignh(x.c,x.d), s4=alignh(x.d,Rv);
    R4 m; m.a=pmax3(s0,x.a,s1); m.b=pmax3(s1,x.b,s2); m.c=pmax3(s2,x.c,s3); m.d=pmax3(s3,x.d,s4);
    return m;
}

// One pipeline step (round-4-verified dataflow, f16). Window shift by name
// rotation at the call site — no arrays (rule #20).
__device__ __forceinline__ void step_body(
    int g, int s, int y0, int y1,
    int upA, int dnA, bool l0, bool l63,
    const float* __restrict__ img, const float* __restrict__ oth,
    R4& i2, R4& i1, R4& i0next,
    R4& e1p, R4& e1pp, R4& e2p, R4& e2pp, R4& e3p, R4& e3pp,
    R4& h1p, R4& h1pp, R4& h2p, R4& h2pp, R4& h3p, R4& h3pp,
    R4& h4p, R4& h4pp,
    R4& skB, R4& skD1, R4& skD2, R4& skF,
    float& sa, float& sb)
{
    R4 i0 = i0next;
    {   // prefetch next input row
        const int gn = g + 1;
        const bool ld = (s + 1 < BAND + 10) && (gn >= 0) && (gn < HH);
        i0next = ld ? ldrow(img + (size_t)gn * WW) : r4splat(PINF2);
    }
    const int  yf  = g - 5;                  // row finished this step
    const bool fin = (yf >= y0) && (yf < y1);
    float4 o1, o2;
    if (fin) {
        o1 = *(const float4*)(oth + (size_t)yf * WW);
        o2 = *(const float4*)(oth + (size_t)yf * WW + 4);
    }

    // ---- stage 1: e1(g-1) ----
    R4 e1n = rmin(vmin3(i2, i1, i0), hmin3w(i1, upA, dnA, l0, l63));
    R4 h1n = hmax3w(e1n, upA, dnA, l0, l63);
    if ((unsigned)(g - 1) >= (unsigned)HH) { e1n = r4splat(PINF2); h1n = r4splat(NINF2); }
    R4 d1 = rmax3(h1pp, h1p, h1n);           // dilate(e1) at row g-2
    skB = relusub(i2, d1);                   // skel init for row g-2

    // ---- stage 2: e2(g-2) ----
    R4 e2n = rmin(vmin3(e1pp, e1p, e1n), hmin3w(e1p, upA, dnA, l0, l63));
    R4 h2n = hmax3w(e2n, upA, dnA, l0, l63);
    if ((unsigned)(g - 2) >= (unsigned)HH) { e2n = r4splat(PINF2); h2n = r4splat(NINF2); }
    R4 d2 = rmax3(h2pp, h2p, h2n);           // dilate(e2) at row g-3
    skupd(skD1, relusub(e1pp, d2));

    // ---- stage 3: e3(g-3) ----
    R4 e3n = rmin(vmin3(e2pp, e2p, e2n), hmin3w(e2p, upA, dnA, l0, l63));
    R4 h3n = hmax3w(e3n, upA, dnA, l0, l63);
    if ((unsigned)(g - 3) >= (unsigned)HH) { e3n = r4splat(PINF2); h3n = r4splat(NINF2); }
    R4 d3 = rmax3(h3pp, h3p, h3n);           // dilate(e3) at row g-4
    skupd(skD2, relusub(e2pp, d3));

    // ---- stage 4: e4(g-4) ----
    R4 e4n = rmin(vmin3(e3pp, e3p, e3n), hmin3w(e3p, upA, dnA, l0, l63));
    R4 h4n = hmax3w(e4n, upA, dnA, l0, l63);
    if ((unsigned)(g - 4) >= (unsigned)HH) { h4n = r4splat(NINF2); }
    R4 d4 = rmax3(h4pp, h4p, h4n);           // dilate(e4) at row g-5
    skupd(skF, relusub(e3pp, d4));

    // ---- finish row g-5 ----
    if (fin) {
        float f0=lo_f(skF.a), f1=hi_f(skF.a), f2=lo_f(skF.b), f3=hi_f(skF.b);
        float f4=lo_f(skF.c), f5=hi_f(skF.c), f6=lo_f(skF.d), f7=hi_f(skF.d);
        sa += ((f0+f1)+(f2+f3)) + ((f4+f5)+(f6+f7));
        sb += ((f0*o1.x + f1*o1.y) + (f2*o1.z + f3*o1.w))
            + ((f4*o2.x + f5*o2.y) + (f6*o2.z + f7*o2.w));
    }

    // ---- shift: new row overwrites pp slot; caller swaps (p,pp) next call ----
    i2 = i1; i1 = i0;
    e1pp = e1n; e2pp = e2n; e3pp = e3n;
    h1pp = h1n; h2pp = h2n; h3pp = h3n; h4pp = h4n;
}

__global__ __launch_bounds__(256, 2)
void cldice_stream_k(const float* __restrict__ y_pred,
                     const float* __restrict__ y_true,
                     float2* __restrict__ partials, int B)
{
    const int lane = threadIdx.x & 63;
    const int wid  = threadIdx.x >> 6;
    const int wave = blockIdx.x * 4 + wid;
    const int nPerChain = B * NBANDS;
    if (wave >= 2 * nPerChain) return;
    const int chain = wave / nPerChain;
    const int rem   = wave - chain * nPerChain;
    const int im    = rem >> 5;                 // NBANDS == 32
    const int band  = rem & (NBANDS - 1);
    const int y0 = band * BAND;
    const int y1 = y0 + BAND;

    const float* __restrict__ img = (chain ? y_true : y_pred) + (size_t)im * NPIX + lane * 8;
    const float* __restrict__ oth = (chain ? y_pred : y_true) + (size_t)im * NPIX + lane * 8;

    const int  upA = ((lane + 63) & 63) << 2;   // bpermute byte addr of lane-1
    const int  dnA = ((lane + 1)  & 63) << 2;   // bpermute byte addr of lane+1
    const bool l0  = (lane == 0);
    const bool l63 = (lane == 63);

    // named register state — NO arrays anywhere
    R4 i2 = r4splat(PINF2), i1 = i2;
    R4 e1A = i2, e1B = i2, e2A = i2, e2B = i2, e3A = i2, e3B = i2;
    R4 h1A = r4splat(NINF2), h1B = h1A, h2A = h1A, h2B = h1A;
    R4 h3A = h1A, h3B = h1A, h4A = h1A, h4B = h1A;
    R4 sk0 = r4splat(0u), sk1 = sk0, sk2 = sk0, sk3 = sk0;
    float sa = 0.f, sb = 0.f;

    const int g0 = y0 - 5;
    R4 i0next = (g0 >= 0) ? ldrow(img + (size_t)g0 * WW) : r4splat(PINF2);

#define STEP(U, E1P,E1PP, E2P,E2PP, E3P,E3PP, H1P,H1PP, H2P,H2PP, H3P,H3PP, H4P,H4PP, SKB,SKD1,SKD2,SKF) \
    step_body(g0 + sbase + U, sbase + U, y0, y1, upA, dnA, l0, l63, img, oth, i2, i1, i0next, \
              E1P,E1PP, E2P,E2PP, E3P,E3PP, H1P,H1PP, H2P,H2PP, H3P,H3PP, H4P,H4PP, \
              SKB,SKD1,SKD2,SKF, sa, sb)

    for (int sbase = 0; sbase < NS; sbase += 4) {
        STEP(0, e1A,e1B, e2A,e2B, e3A,e3B, h1A,h1B, h2A,h2B, h3A,h3B, h4A,h4B, sk1,sk0,sk3,sk2);
        STEP(1, e1B,e1A, e2B,e2A, e3B,e3A, h1B,h1A, h2B,h2A, h3B,h3A, h4B,h4A, sk2,sk1,sk0,sk3);
        STEP(2, e1A,e1B, e2A,e2B, e3A,e3B, h1A,h1B, h2A,h2B, h3A,h3B, h4A,h4B, sk3,sk2,sk1,sk0);
        STEP(3, e1B,e1A, e2B,e2A, e3B,e3A, h1B,h1A, h2B,h2A, h3B,h3A, h4B,h4A, sk0,sk3,sk2,sk1);
    }
#undef STEP

#pragma unroll
    for (int off = 32; off; off >>= 1) {
        sa += __shfl_down(sa, off);
        sb += __shfl_down(sb, off);
    }
    if (lane == 0) partials[wave] = make_float2(sb, sa);   // (.x = sum skel*other, .y = sum skel)
}

__global__ void cldice_final_k(const float2* __restrict__ partials, int nW,
                               float* __restrict__ out)
{
    double s0 = 0, s1 = 0, s2 = 0, s3 = 0;
    for (int i = threadIdx.x; i < nW; i += 256) {
        float2 p = partials[i];        s0 += p.x; s1 += p.y;   // chain 0: skel_pred
        float2 q = partials[nW + i];   s2 += q.x; s3 += q.y;   // chain 1: skel_true
    }
#pragma unroll
    for (int off = 32; off; off >>= 1) {
        s0 += __shfl_down(s0, off);
        s1 += __shfl_down(s1, off);
        s2 += __shfl_down(s2, off);
        s3 += __shfl_down(s3, off);
    }
    __shared__ double sm[4][4];
    int wid = threadIdx.x >> 6, lane = threadIdx.x & 63;
    if (lane == 0) { sm[0][wid] = s0; sm[1][wid] = s1; sm[2][wid] = s2; sm[3][wid] = s3; }
    __syncthreads();
    if (threadIdx.x == 0) {
        double S0 = sm[0][0] + sm[0][1] + sm[0][2] + sm[0][3];
        double S1 = sm[1][0] + sm[1][1] + sm[1][2] + sm[1][3];
        double S2 = sm[2][0] + sm[2][1] + sm[2][2] + sm[2][3];
        double S3 = sm[3][0] + sm[3][1] + sm[3][2] + sm[3][3];
        double tprec = (S0 + 1.0) / (S1 + 1.0);
        double tsens = (S2 + 1.0) / (S3 + 1.0);
        out[0] = (float)(1.0 - 2.0 * (tprec * tsens) / (tprec + tsens));
    }
}

extern "C" void kernel_launch(void* const* d_in, const int* in_sizes, int n_in,
                              void* d_out, int out_size, void* d_ws, size_t ws_size,
                              hipStream_t stream)
{
    const float* y_pred = (const float*)d_in[0];
    const float* y_true = (const float*)d_in[1];
    const int B = in_sizes[0] / NPIX;          // 32 images

    float2* partials = (float2*)d_ws;          // 2*B*NBANDS float2 = 16 KB
    const int nWaves = 2 * B * NBANDS;
    const int blocks = (nWaves + 3) / 4;       // 4 waves per 256-thread block
    cldice_stream_k<<<blocks, 256, 0, stream>>>(y_pred, y_true, partials, B);

    cldice_final_k<<<1, 256, 0, stream>>>(partials, B * NBANDS, (float*)d_out);
}

// Round 12
// 46.985 us; speedup vs baseline: 4.6456x; 1.1751x over previous
//
#include <hip/hip_runtime.h>
#include <hip/hip_fp16.h>

#define HH 512
#define WW 512
#define NPIX (HH*WW)
#define NBANDS 32
#define BAND (HH/NBANDS)     // 16 output rows per wave
#define NS 28                // ceil((BAND+10)/4)*4 streamed steps
#define PINF2 0x7C007C00u    // packed f16 +inf
#define NINF2 0xFC00FC00u    // packed f16 -inf

// ---- packed f16 ops as VOP3P inline asm (proven rounds 8-11) ----
typedef unsigned uh2;
__device__ __forceinline__ uh2 pmin(uh2 a, uh2 b){ uh2 r; asm("v_pk_min_f16 %0, %1, %2" : "=v"(r) : "v"(a), "v"(b)); return r; }
__device__ __forceinline__ uh2 pmax(uh2 a, uh2 b){ uh2 r; asm("v_pk_max_f16 %0, %1, %2" : "=v"(r) : "v"(a), "v"(b)); return r; }
__device__ __forceinline__ uh2 padd(uh2 a, uh2 b){ uh2 r; asm("v_pk_add_f16 %0, %1, %2" : "=v"(r) : "v"(a), "v"(b)); return r; }
__device__ __forceinline__ uh2 psub(uh2 a, uh2 b){ uh2 r; asm("v_pk_add_f16 %0, %1, %2 neg_lo:[0,1] neg_hi:[0,1]" : "=v"(r) : "v"(a), "v"(b)); return r; }
__device__ __forceinline__ uh2 pnfma(uh2 s, uh2 d){ uh2 r; asm("v_pk_fma_f16 %0, %1, %2, %2 neg_lo:[1,0,0] neg_hi:[1,0,0]" : "=v"(r) : "v"(s), "v"(d)); return r; }
__device__ __forceinline__ uh2 pmin3(uh2 a, uh2 b, uh2 c){ return pmin(pmin(a,b),c); }
__device__ __forceinline__ uh2 pmax3(uh2 a, uh2 b, uh2 c){ return pmax(pmax(a,b),c); }
__device__ __forceinline__ uh2 alignh(uh2 lo, uh2 hi){ return (lo >> 16) | (hi << 16); }   // (lo.y, hi.x)
__device__ __forceinline__ uh2 pk2(float x, float y){
    __half2 h = __halves2half2(__float2half_rn(x), __float2half_rn(y));
    union { __half2 h; uh2 u; } c; c.h = h; return c.u;
}
__device__ __forceinline__ float lo_f(uh2 v){ union { uh2 u; __half2 h; } c; c.u = v; return __low2float(c.h); }
__device__ __forceinline__ float hi_f(uh2 v){ union { uh2 u; __half2 h; } c; c.u = v; return __high2float(c.h); }

// ---- DPP full-wave lane shifts (VALU, no DS pipe); invalid lane <- old ----
__device__ __forceinline__ uh2 dshr1(uh2 v, unsigned old){   // lane i <- lane i-1 (wave_shr:1)
    return (uh2)__builtin_amdgcn_update_dpp((int)old, (int)v, 0x138, 0xF, 0xF, false);
}
__device__ __forceinline__ uh2 dshl1(uh2 v, unsigned old){   // lane i <- lane i+1 (wave_shl:1)
    return (uh2)__builtin_amdgcn_update_dpp((int)old, (int)v, 0x130, 0xF, 0xF, false);
}

// one full 512-wide row: lane l holds halves [8l..8l+7] in 4 packed regs
struct R4 { uh2 a, b, c, d; };
__device__ __forceinline__ R4 r4splat(uh2 v){ R4 r; r.a=v; r.b=v; r.c=v; r.d=v; return r; }
__device__ __forceinline__ R4 ldrow(const float* p){
    float4 u = *(const float4*)p;
    float4 v = *(const float4*)(p + 4);
    R4 r; r.a = pk2(u.x,u.y); r.b = pk2(u.z,u.w); r.c = pk2(v.x,v.y); r.d = pk2(v.z,v.w);
    return r;
}
__device__ __forceinline__ R4 vmin3(const R4& x, const R4& y, const R4& z){
    R4 r; r.a=pmin3(x.a,y.a,z.a); r.b=pmin3(x.b,y.b,z.b); r.c=pmin3(x.c,y.c,z.c); r.d=pmin3(x.d,y.d,z.d); return r;
}
__device__ __forceinline__ R4 vmax3(const R4& x, const R4& y, const R4& z){
    R4 r; r.a=pmax3(x.a,y.a,z.a); r.b=pmax3(x.b,y.b,z.b); r.c=pmax3(x.c,y.c,z.c); r.d=pmax3(x.d,y.d,z.d); return r;
}
__device__ __forceinline__ R4 rmin(const R4& x, const R4& y){
    R4 r; r.a=pmin(x.a,y.a); r.b=pmin(x.b,y.b); r.c=pmin(x.c,y.c); r.d=pmin(x.d,y.d); return r;
}
__device__ __forceinline__ R4 rmax3(const R4& x, const R4& y, const R4& z){ return vmax3(x,y,z); }
__device__ __forceinline__ R4 relusub(const R4& p, const R4& d){
    R4 r; r.a=pmax(psub(p.a,d.a),0u); r.b=pmax(psub(p.b,d.b),0u);
          r.c=pmax(psub(p.c,d.c),0u); r.d=pmax(psub(p.d,d.d),0u); return r;
}
// s += d*(1-s)  (relu provably redundant for s,d in [0,1])
__device__ __forceinline__ void skupd2(R4& s, const R4& d){
    s.a = padd(s.a, pnfma(s.a,d.a));
    s.b = padd(s.b, pnfma(s.b,d.b));
    s.c = padd(s.c, pnfma(s.c,d.c));
    s.d = padd(s.d, pnfma(s.d,d.d));
}
// erode horizontal: min(left,right) excluding center (center is in the vertical min)
__device__ __forceinline__ R4 hminLR(const R4& x){
    uh2 L  = dshr1(x.d, PINF2);
    uh2 Rv = dshl1(x.a, PINF2);
    uh2 s0=alignh(L,x.a), s1=alignh(x.a,x.b), s2=alignh(x.b,x.c), s3=alignh(x.c,x.d), s4=alignh(x.d,Rv);
    R4 m; m.a=pmin(s0,s1); m.b=pmin(s1,s2); m.c=pmin(s2,s3); m.d=pmin(s3,s4); return m;
}
// dilate horizontal: 3-window max including center
__device__ __forceinline__ R4 hmax3w(const R4& x){
    uh2 L  = dshr1(x.d, NINF2);
    uh2 Rv = dshl1(x.a, NINF2);
    uh2 s0=alignh(L,x.a), s1=alignh(x.a,x.b), s2=alignh(x.b,x.c), s3=alignh(x.c,x.d), s4=alignh(x.d,Rv);
    R4 m; m.a=pmax3(s0,x.a,s1); m.b=pmax3(s1,x.b,s2); m.c=pmax3(s2,x.c,s3); m.d=pmax3(s3,x.d,s4); return m;
}

// ---------- FAST step: interior bands, no row guards, vertical-first dilate ----------
__device__ __forceinline__ void step_fast(
    int g, int s, int y0, int y1,
    const float* __restrict__ img, const float* __restrict__ oth,
    R4& i2, R4& i1, R4& i0next,
    R4& e1p, R4& e1pp, R4& e2p, R4& e2pp, R4& e3p, R4& e3pp, R4& e4p, R4& e4pp,
    R4& skB, R4& skD1, R4& skD2, R4& skF,
    float& sa, float& sb)
{
    R4 i0 = i0next;
    if (s + 1 < BAND + 10) i0next = ldrow(img + (size_t)(g + 1) * WW);
    const int  yf  = g - 5;
    const bool fin = (yf >= y0) && (yf < y1);
    float4 o1, o2;
    if (fin) {
        o1 = *(const float4*)(oth + (size_t)yf * WW);
        o2 = *(const float4*)(oth + (size_t)yf * WW + 4);
    }

    R4 e1n = rmin(vmin3(i2, i1, i0), hminLR(i1));
    R4 d1  = hmax3w(vmax3(e1pp, e1p, e1n));        // dilate(e1) @ g-2
    skB = relusub(i2, d1);

    R4 e2n = rmin(vmin3(e1pp, e1p, e1n), hminLR(e1p));
    R4 d2  = hmax3w(vmax3(e2pp, e2p, e2n));        // @ g-3
    skupd2(skD1, relusub(e1pp, d2));

    R4 e3n = rmin(vmin3(e2pp, e2p, e2n), hminLR(e2p));
    R4 d3  = hmax3w(vmax3(e3pp, e3p, e3n));        // @ g-4
    skupd2(skD2, relusub(e2pp, d3));

    R4 e4n = rmin(vmin3(e3pp, e3p, e3n), hminLR(e3p));
    R4 d4  = hmax3w(vmax3(e4pp, e4p, e4n));        // @ g-5
    skupd2(skF, relusub(e3pp, d4));

    if (fin) {
        float f0=lo_f(skF.a), f1=hi_f(skF.a), f2=lo_f(skF.b), f3=hi_f(skF.b);
        float f4=lo_f(skF.c), f5=hi_f(skF.c), f6=lo_f(skF.d), f7=hi_f(skF.d);
        sa += ((f0+f1)+(f2+f3)) + ((f4+f5)+(f6+f7));
        sb += ((f0*o1.x + f1*o1.y) + (f2*o1.z + f3*o1.w))
            + ((f4*o2.x + f5*o2.y) + (f6*o2.z + f7*o2.w));
    }
    i2 = i1; i1 = i0;
    e1pp = e1n; e2pp = e2n; e3pp = e3n; e4pp = e4n;   // caller swaps (p,pp)
}

// ---------- GUARD step: bands 0 / NBANDS-1 (round-11-proven logic, DPP) ----------
__device__ __forceinline__ void step_guard(
    int g, int s, int y0, int y1,
    const float* __restrict__ img, const float* __restrict__ oth,
    R4& i2, R4& i1, R4& i0next,
    R4& e1p, R4& e1pp, R4& e2p, R4& e2pp, R4& e3p, R4& e3pp,
    R4& h1p, R4& h1pp, R4& h2p, R4& h2pp, R4& h3p, R4& h3pp,
    R4& h4p, R4& h4pp,
    R4& skB, R4& skD1, R4& skD2, R4& skF,
    float& sa, float& sb)
{
    R4 i0 = i0next;
    {
        const int gn = g + 1;
        const bool ld = (s + 1 < BAND + 10) && (gn >= 0) && (gn < HH);
        i0next = ld ? ldrow(img + (size_t)gn * WW) : r4splat(PINF2);
    }
    const int  yf  = g - 5;
    const bool fin = (yf >= y0) && (yf < y1);
    float4 o1, o2;
    if (fin) {
        o1 = *(const float4*)(oth + (size_t)yf * WW);
        o2 = *(const float4*)(oth + (size_t)yf * WW + 4);
    }

    R4 e1n = rmin(vmin3(i2, i1, i0), hminLR(i1));
    R4 h1n = hmax3w(e1n);
    if ((unsigned)(g - 1) >= (unsigned)HH) { e1n = r4splat(PINF2); h1n = r4splat(NINF2); }
    R4 d1 = rmax3(h1pp, h1p, h1n);
    skB = relusub(i2, d1);

    R4 e2n = rmin(vmin3(e1pp, e1p, e1n), hminLR(e1p));
    R4 h2n = hmax3w(e2n);
    if ((unsigned)(g - 2) >= (unsigned)HH) { e2n = r4splat(PINF2); h2n = r4splat(NINF2); }
    R4 d2 = rmax3(h2pp, h2p, h2n);
    skupd2(skD1, relusub(e1pp, d2));

    R4 e3n = rmin(vmin3(e2pp, e2p, e2n), hminLR(e2p));
    R4 h3n = hmax3w(e3n);
    if ((unsigned)(g - 3) >= (unsigned)HH) { e3n = r4splat(PINF2); h3n = r4splat(NINF2); }
    R4 d3 = rmax3(h3pp, h3p, h3n);
    skupd2(skD2, relusub(e2pp, d3));

    R4 e4n = rmin(vmin3(e3pp, e3p, e3n), hminLR(e3p));
    R4 h4n = hmax3w(e4n);
    if ((unsigned)(g - 4) >= (unsigned)HH) { h4n = r4splat(NINF2); }
    R4 d4 = rmax3(h4pp, h4p, h4n);
    skupd2(skF, relusub(e3pp, d4));

    if (fin) {
        float f0=lo_f(skF.a), f1=hi_f(skF.a), f2=lo_f(skF.b), f3=hi_f(skF.b);
        float f4=lo_f(skF.c), f5=hi_f(skF.c), f6=lo_f(skF.d), f7=hi_f(skF.d);
        sa += ((f0+f1)+(f2+f3)) + ((f4+f5)+(f6+f7));
        sb += ((f0*o1.x + f1*o1.y) + (f2*o1.z + f3*o1.w))
            + ((f4*o2.x + f5*o2.y) + (f6*o2.z + f7*o2.w));
    }
    i2 = i1; i1 = i0;
    e1pp = e1n; e2pp = e2n; e3pp = e3n;
    h1pp = h1n; h2pp = h2n; h3pp = h3n; h4pp = h4n;
}

__global__ __launch_bounds__(256, 2)
void cldice_stream_k(const float* __restrict__ y_pred,
                     const float* __restrict__ y_true,
                     float2* __restrict__ partials, int B)
{
    const int lane = threadIdx.x & 63;
    const int wid  = threadIdx.x >> 6;
    const int wave = blockIdx.x * 4 + wid;
    const int nPerChain = B * NBANDS;
    if (wave >= 2 * nPerChain) return;
    const int chain = wave / nPerChain;
    const int rem   = wave - chain * nPerChain;
    const int im    = rem >> 5;                 // NBANDS == 32
    const int band  = rem & (NBANDS - 1);
    const int y0 = band * BAND;
    const int y1 = y0 + BAND;

    const float* __restrict__ img = (chain ? y_true : y_pred) + (size_t)im * NPIX + lane * 8;
    const float* __restrict__ oth = (chain ? y_pred : y_true) + (size_t)im * NPIX + lane * 8;

    R4 sk0 = r4splat(0u), sk1 = sk0, sk2 = sk0, sk3 = sk0;
    float sa = 0.f, sb = 0.f;
    const int g0 = y0 - 5;

    if (band == 0 || band == NBANDS - 1) {
        // -------- guarded path (image top/bottom) --------
        R4 i2 = r4splat(PINF2), i1 = i2;
        R4 e1A = i2, e1B = i2, e2A = i2, e2B = i2, e3A = i2, e3B = i2;
        R4 h1A = r4splat(NINF2), h1B = h1A, h2A = h1A, h2B = h1A;
        R4 h3A = h1A, h3B = h1A, h4A = h1A, h4B = h1A;
        R4 i0next = (g0 >= 0) ? ldrow(img + (size_t)g0 * WW) : r4splat(PINF2);

#define STEPG(U, E1P,E1PP, E2P,E2PP, E3P,E3PP, H1P,H1PP, H2P,H2PP, H3P,H3PP, H4P,H4PP, SKB,SKD1,SKD2,SKF) \
        step_guard(g0 + sbase + U, sbase + U, y0, y1, img, oth, i2, i1, i0next, \
                   E1P,E1PP, E2P,E2PP, E3P,E3PP, H1P,H1PP, H2P,H2PP, H3P,H3PP, H4P,H4PP, \
                   SKB,SKD1,SKD2,SKF, sa, sb)
        for (int sbase = 0; sbase < NS; sbase += 4) {
            STEPG(0, e1A,e1B, e2A,e2B, e3A,e3B, h1A,h1B, h2A,h2B, h3A,h3B, h4A,h4B, sk1,sk0,sk3,sk2);
            STEPG(1, e1B,e1A, e2B,e2A, e3B,e3A, h1B,h1A, h2B,h2A, h3B,h3A, h4B,h4A, sk2,sk1,sk0,sk3);
            STEPG(2, e1A,e1B, e2A,e2B, e3A,e3B, h1A,h1B, h2A,h2B, h3A,h3B, h4A,h4B, sk3,sk2,sk1,sk0);
            STEPG(3, e1B,e1A, e2B,e2A, e3B,e3A, h1B,h1A, h2B,h2A, h3B,h3A, h4B,h4A, sk0,sk3,sk2,sk1);
        }
#undef STEPG
    } else {
        // -------- fast path (interior bands; all halo rows are real) --------
        R4 i2 = ldrow(img + (size_t)g0 * WW);       // harmless warm init (rows valid)
        R4 i1 = i2;
        R4 e1A = r4splat(PINF2), e1B = e1A, e2A = e1A, e2B = e1A;
        R4 e3A = e1A, e3B = e1A, e4A = e1A, e4B = e1A;
        R4 i0next = i2;

#define STEPF(U, E1P,E1PP, E2P,E2PP, E3P,E3PP, E4P,E4PP, SKB,SKD1,SKD2,SKF) \
        step_fast(g0 + sbase + U, sbase + U, y0, y1, img, oth, i2, i1, i0next, \
                  E1P,E1PP, E2P,E2PP, E3P,E3PP, E4P,E4PP, SKB,SKD1,SKD2,SKF, sa, sb)
        for (int sbase = 0; sbase < NS; sbase += 4) {
            STEPF(0, e1A,e1B, e2A,e2B, e3A,e3B, e4A,e4B, sk1,sk0,sk3,sk2);
            STEPF(1, e1B,e1A, e2B,e2A, e3B,e3A, e4B,e4A, sk2,sk1,sk0,sk3);
            STEPF(2, e1A,e1B, e2A,e2B, e3A,e3B, e4A,e4B, sk3,sk2,sk1,sk0);
            STEPF(3, e1B,e1A, e2B,e2A, e3B,e3A, e4B,e4A, sk0,sk3,sk2,sk1);
        }
#undef STEPF
    }

#pragma unroll
    for (int off = 32; off; off >>= 1) {
        sa += __shfl_down(sa, off);
        sb += __shfl_down(sb, off);
    }
    if (lane == 0) partials[wave] = make_float2(sb, sa);   // (.x = sum skel*other, .y = sum skel)
}

__global__ void cldice_final_k(const float2* __restrict__ partials, int nW,
                               float* __restrict__ out)
{
    double s0 = 0, s1 = 0, s2 = 0, s3 = 0;
    for (int i = threadIdx.x; i < nW; i += 256) {
        float2 p = partials[i];        s0 += p.x; s1 += p.y;   // chain 0: skel_pred
        float2 q = partials[nW + i];   s2 += q.x; s3 += q.y;   // chain 1: skel_true
    }
#pragma unroll
    for (int off = 32; off; off >>= 1) {
        s0 += __shfl_down(s0, off);
        s1 += __shfl_down(s1, off);
        s2 += __shfl_down(s2, off);
        s3 += __shfl_down(s3, off);
    }
    __shared__ double sm[4][4];
    int wid = threadIdx.x >> 6, lane = threadIdx.x & 63;
    if (lane == 0) { sm[0][wid] = s0; sm[1][wid] = s1; sm[2][wid] = s2; sm[3][wid] = s3; }
    __syncthreads();
    if (threadIdx.x == 0) {
        double S0 = sm[0][0] + sm[0][1] + sm[0][2] + sm[0][3];
        double S1 = sm[1][0] + sm[1][1] + sm[1][2] + sm[1][3];
        double S2 = sm[2][0] + sm[2][1] + sm[2][2] + sm[2][3];
        double S3 = sm[3][0] + sm[3][1] + sm[3][2] + sm[3][3];
        double tprec = (S0 + 1.0) / (S1 + 1.0);
        double tsens = (S2 + 1.0) / (S3 + 1.0);
        out[0] = (float)(1.0 - 2.0 * (tprec * tsens) / (tprec + tsens));
    }
}

extern "C" void kernel_launch(void* const* d_in, const int* in_sizes, int n_in,
                              void* d_out, int out_size, void* d_ws, size_t ws_size,
                              hipStream_t stream)
{
    const float* y_pred = (const float*)d_in[0];
    const float* y_true = (const float*)d_in[1];
    const int B = in_sizes[0] / NPIX;          // 32 images

    float2* partials = (float2*)d_ws;          // 2*B*NBANDS float2 = 16 KB
    const int nWaves = 2 * B * NBANDS;
    const int blocks = (nWaves + 3) / 4;       // 4 waves per 256-thread block
    cldice_stream_k<<<blocks, 256, 0, stream>>>(y_pred, y_true, partials, B);

    cldice_final_k<<<1, 256, 0, stream>>>(partials, B * NBANDS, (float*)d_out);
}